// Round 6
// baseline (582.695 us; speedup 1.0000x reference)
//
#include <hip/hip_runtime.h>
#include <hip/hip_bf16.h>
#include <math.h>

typedef __attribute__((ext_vector_type(4))) float f32x4;
typedef __attribute__((ext_vector_type(2))) float f32x2;
typedef __attribute__((ext_vector_type(8))) short s16x8;
typedef __attribute__((ext_vector_type(4))) short s16x4;
typedef __hip_bfloat16 bf16;

#define MB (1024ull*1024ull)
// workspace layout (bytes)
#define GATE_OFF    (0ull)
#define ACTW_OFF    (16ull*1024)
#define U_OFF       (20ull*1024)      // uvec 2048 f32 + cmean 1024 f32 contiguous
#define CMEAN_OFF   (28ull*1024)
#define HIDDEN_OFF  (1ull*MB)
#define RATT_OFF    (5ull*MB)
#define CAND_OFF    (9ull*MB)
#define PREDS_OFF   (11ull*MB)
#define READ_OFF    (13ull*MB)
#define XBF_OFF     (17ull*MB)
#define WT_OFF      (19ull*MB)      // bf16 8192x1024 (16MB); G5 partials alias head after G1
#define CATT_OFF    (35ull*MB)      // bf16 3584x2048 (14MB)
#define MEMT_OFF    (49ull*MB)      // bf16 1024x2048 (4MB)
#define CTR_OFF     (60ull*MB)      // dependency counters (memset to 0 each launch)
#define READ2_OFF   WT_OFF

__device__ __forceinline__ short f2bf_s(float f) {
    bf16 h = __float2bfloat16(f);
    return *reinterpret_cast<short*>(&h);
}

__device__ __forceinline__ void async_load16(const bf16* g, short* l) {
    __builtin_amdgcn_global_load_lds((const __attribute__((address_space(1))) void*)g,
                                     (__attribute__((address_space(3))) void*)l, 16, 0, 0);
}

__device__ __forceinline__ float fast_tanh(float x) {
    float e2x = __expf(2.f * x);
    return 1.f - 2.f / (e2x + 1.f);
}

// ---------------- intra-dispatch dependency counters ----------------
// Producer: __syncthreads (drains this block's stores: compiler emits vmcnt(0) before
// s_barrier), then thread0 device-fence + device-scope atomicAdd.
// Consumer: thread0 polls with atomicAdd(c,0) (RMW bypasses caches) + s_sleep, fences
// (L1/L2 invalidate) BEFORE releasing the block through __syncthreads.
// Deadlock-free by capacity: spinner blocks < resident capacity in every dispatch, so
// productive blocks always have free slots — no dispatch-order assumption needed.
__device__ __forceinline__ void bump_ctr(unsigned* c) {
    __syncthreads();
    if (threadIdx.x == 0) { __threadfence(); atomicAdd(c, 1u); }
}
__device__ __forceinline__ void wait_ctr(unsigned* c, unsigned tgt) {
    if (threadIdx.x == 0) {
        while (atomicAdd(c, 0u) < tgt) __builtin_amdgcn_s_sleep(8);
        __threadfence();
    }
    __syncthreads();
}

// fast 9-way activation mix — __expf algebra only (validated round 9)
__device__ __forceinline__ float qact(float x, const float* w) {
    float ex  = __expf(x);
    float r1  = 1.f / (1.f + ex);
    float sig = 1.f - r1;
    float em1 = ex - 1.f;
    float elu = x > 0.f ? x : em1;
    float e2x = ex * ex;
    float th  = 1.f - 2.f / (e2x + 1.f);
    float rel = fmaxf(x, 0.f);
    float silu = x * sig;
    float u   = 0.7978845608028654f * (x + 0.044715f * x * x * x);
    float e2u = __expf(2.f * u);
    float gel = x * (1.f - 1.f / (e2u + 1.f));
    float sel = 1.0507009873554805f * (x > 0.f ? x : 1.6732632423543772f * em1);
    float t   = 1.f + ex;
    float t2  = t * t;
    float mish = x * (1.f - 2.f / (t2 + 1.f));
    return w[0]*sig + w[1]*elu + w[2]*th + w[3]*rel + w[4]*silu
         + w[5]*gel + w[6]*sel + w[7]*mish + w[8]*x;
}

// ---------------- 64x64 f32 -> bf16 transpose tile (f32x2 loads; scratch 64x66 shorts) ----------------
__device__ __forceinline__ void do_transpose(const float* __restrict__ in,
                                             bf16* __restrict__ out, int R, int C,
                                             int bx, int by, int t, short* tile) {
    int k0 = by*64, n0 = bx*64;
    int i = t & 31, half = t >> 5;            // half = 0..7 over 256 threads
    #pragma unroll
    for (int r = 0; r < 8; r++) {
        int k = half + r*8;
        f32x2 v = *reinterpret_cast<const f32x2*>(&in[(size_t)(k0 + k)*C + n0 + i*2]);
        tile[(i*2 + 0)*66 + k] = f2bf_s(v[0]);
        tile[(i*2 + 1)*66 + k] = f2bf_s(v[1]);
    }
    __syncthreads();
    int kp = t & 31, nrow = t >> 5;
    #pragma unroll
    for (int jj = 0; jj < 8; jj++) {
        int n = nrow + jj*8;
        unsigned lo = (unsigned short)tile[n*66 + kp*2];
        unsigned hi = (unsigned short)tile[n*66 + kp*2 + 1];
        *reinterpret_cast<unsigned*>(&out[(size_t)(n0 + n)*R + k0 + kp*2]) = lo | (hi << 16);
    }
}

// ---------------- GEMM (BT): C = A(MxK) @ Bt(NxK)^T, TMx128 tile, BK=32 ----------------
// Round 15: LDS k-slot XOR swizzle (SQ_LDS_BANK_CONFLICT 2.36M -> 262K, verified).
// Round 16: triple-buffered K-loop, counted vmcnt (never 0 mid-loop), raw s_barrier.
template <int TM>
union SMemT {
    struct { short a[3][TM*32]; short b[3][128*32]; } tl;
    float z[TM*32];
    short tr[64*66];
};

template <int MODE, int TM>
__device__ __forceinline__ void gemm_core(
        int bx, int by, int bz, SMemT<TM>& sm,
        const bf16* __restrict__ A, const bf16* __restrict__ Bt,
        int K, int lda, int ldb, int kOffset,
        const float* __restrict__ bias, const float* __restrict__ bias2,
        const float* __restrict__ bias3,
        float* __restrict__ outF, float* __restrict__ outF2,
        bf16* __restrict__ outH, bf16* __restrict__ outH2,
        const float* __restrict__ gate, const float* __restrict__ actw,
        const float* __restrict__ mask, int outStride) {
    constexpr int MI = TM / 32;
    int t = threadIdx.x, lane = t & 63;
    int rowBase = by * TM, colBase = bx * 128;
    int lm = lane & 15, lq = lane >> 4;
    int w = t >> 6;
    int qm = (w >> 1) * (TM/2), qn = (w & 1) * 64;

    A  += (size_t)kOffset * bz;
    Bt += (size_t)kOffset * bz;

    f32x4 acc[MI][4];
    #pragma unroll
    for (int i = 0; i < MI; i++)
        #pragma unroll
        for (int j = 0; j < 4; j++) acc[i][j] = (f32x4){0.f, 0.f, 0.f, 0.f};

    // B staging: chunks c = w*128 + lane (+64); source k pre-swizzled: s' = s ^ ((row>>1)&3)
    int cb0 = w*128 + lane, cb1 = cb0 + 64;
    int rb0 = cb0 >> 2, kb0 = ((cb0 & 3) ^ ((rb0 >> 1) & 3)) * 8;
    int rb1 = cb1 >> 2, kb1 = ((cb1 & 3) ^ ((rb1 >> 1) & 3)) * 8;
    // A staging
    int ca0 = (TM == 128) ? (w*128 + lane) : (w*64 + lane);
    int ra0 = ca0 >> 2, ka0 = ((ca0 & 3) ^ ((ra0 >> 1) & 3)) * 8;
    int ca1 = ca0 + 64;
    int ra1 = ca1 >> 2, ka1 = ((ca1 & 3) ^ ((ra1 >> 1) & 3)) * 8;   // TM=128 only

    auto issueLoads = [&](int k0, int ib) {
        short* bA = sm.tl.a[ib];
        short* bB = sm.tl.b[ib];
        async_load16(A + (size_t)(rowBase + ra0)*lda + k0 + ka0,
                     bA + ((TM == 128) ? w*1024 : w*512));
        if (TM == 128)
            async_load16(A + (size_t)(rowBase + ra1)*lda + k0 + ka1, bA + w*1024 + 512);
        async_load16(Bt + (size_t)(colBase + rb0)*ldb + k0 + kb0, bB + w*1024);
        async_load16(Bt + (size_t)(colBase + rb1)*ldb + k0 + kb1, bB + w*1024 + 512);
    };

    issueLoads(0, 0);
    if (32 < K) issueLoads(32, 1);
    int ib = 0;
    for (int k0 = 0; k0 < K; k0 += 32) {
        // wait for THIS step's loads only; k+1/k+2 stay in flight across the barrier (T4)
        if (k0 + 32 < K) {
            if (TM == 128) asm volatile("s_waitcnt vmcnt(4)" ::: "memory");
            else           asm volatile("s_waitcnt vmcnt(3)" ::: "memory");
        } else {
            asm volatile("s_waitcnt vmcnt(0)" ::: "memory");
        }
        __builtin_amdgcn_sched_barrier(0);
        __builtin_amdgcn_s_barrier();
        __builtin_amdgcn_sched_barrier(0);
        int ibn = ib + 2; if (ibn >= 3) ibn -= 3;
        if (k0 + 64 < K) issueLoads(k0 + 64, ibn);
        const short* cA = sm.tl.a[ib];
        const short* cB = sm.tl.b[ib];
        s16x8 af[MI], bfr[4];
        #pragma unroll
        for (int mi = 0; mi < MI; mi++) {
            int r = qm + mi*16 + lm;
            af[mi] = *reinterpret_cast<const s16x8*>(cA + r*32 + ((lq ^ ((r >> 1) & 3)) * 8));
        }
        #pragma unroll
        for (int ni = 0; ni < 4; ni++) {
            int r = qn + ni*16 + lm;
            bfr[ni] = *reinterpret_cast<const s16x8*>(cB + r*32 + ((lq ^ ((r >> 1) & 3)) * 8));
        }
        #pragma unroll
        for (int mi = 0; mi < MI; mi++)
            #pragma unroll
            for (int ni = 0; ni < 4; ni++)
                acc[mi][ni] = __builtin_amdgcn_mfma_f32_16x16x32_bf16(af[mi], bfr[ni], acc[mi][ni], 0, 0, 0);
        ib += 1; if (ib >= 3) ib = 0;
    }

    if (MODE == 4) {
        __syncthreads();   // all tile reads done; safe to overlay sm.z
        #pragma unroll
        for (int mi = 0; mi < MI; mi++) {
            int rowl0 = qm + mi*16 + lq*4;
            #pragma unroll
            for (int ni = 0; ni < 4; ni++) {
                int col = colBase + qn + ni*16 + lm;
                int n = col & 3;
                float bb = bias[col];
                f32x4 v = acc[mi][ni];
                #pragma unroll
                for (int r = 0; r < 4; r++) v[r] = (v[r] + bb) * gate[(rowBase + rowl0 + r)*4 + n];
                #pragma unroll
                for (int r = 0; r < 4; r++) v[r] += __shfl_xor(v[r], 1);
                #pragma unroll
                for (int r = 0; r < 4; r++) v[r] += __shfl_xor(v[r], 2);
                if ((lane & 3) == 0) {
                    int ul = ((w & 1) << 4) + ni*4 + (lm >> 2);
                    #pragma unroll
                    for (int r = 0; r < 4; r++)
                        sm.z[(rowl0 + r)*32 + ul] = v[r];
                }
            }
        }
        __syncthreads();
        float aw[9];
        #pragma unroll
        for (int i = 0; i < 9; i++) aw[i] = actw[i];
        int u0 = colBase >> 2;
        #pragma unroll
        for (int i = 0; i < TM/8; i++) {
            int idx = t + i*256;
            int row = idx >> 5, ul = idx & 31;
            int ug = u0 + ul;
            float zz = sm.z[idx];
            outH[(size_t)(rowBase + row)*outStride + ug] = __float2bfloat16(qact(zz, aw) * mask[ug]);
        }
    } else if (MODE == 5) {
        #pragma unroll
        for (int mi = 0; mi < MI; mi++) {
            int row0 = rowBase + qm + mi*16 + lq*4;
            #pragma unroll
            for (int ni = 0; ni < 4; ni++) {
                int col = colBase + qn + ni*16 + lm;
                if (col < 2048) {
                    float bb = bias[col];
                    #pragma unroll
                    for (int r = 0; r < 4; r++)
                        outH[(size_t)(row0 + r)*2048 + col] = __float2bfloat16(acc[mi][ni][r] + bb);
                } else if (col < 3072) {
                    int c = col - 2048;
                    float bb = bias2[c];
                    #pragma unroll
                    for (int r = 0; r < 4; r++)
                        outH2[(size_t)(row0 + r)*1024 + c] = __float2bfloat16(fast_tanh(acc[mi][ni][r] + bb));
                } else {
                    int c = col - 3072;
                    float bb = bias3[c];
                    #pragma unroll
                    for (int r = 0; r < 4; r++)
                        outF[(size_t)(row0 + r)*512 + c] = acc[mi][ni][r] + bb;
                }
            }
        }
    } else {  // MODE 3 (split-K partial, z in [0,4): partial 0 -> outF, z>0 -> outF2 + (z-1)*1M floats)
        float* of = bz ? (outF2 + (size_t)(bz - 1) * 1048576) : outF;
        #pragma unroll
        for (int mi = 0; mi < MI; mi++) {
            int row0 = rowBase + qm + mi*16 + lq*4;
            #pragma unroll
            for (int ni = 0; ni < 4; ni++) {
                int col = colBase + qn + ni*16 + lm;
                #pragma unroll
                for (int r = 0; r < 4; r++)
                    of[(size_t)(row0 + r)*outStride + col] = acc[mi][ni][r];
            }
        }
    }
}

// ================= MEGA 1: prepass (counted) + G1 gemm (spin) + trailing transposes =================
// Block map: [0,4099) stage-1 units (bump ctr1): [0,2048) wT transpose; [2048,3072) cvt;
// [3072,4096) gate; [4096,4099) zero uvec/cmean. [4099,4611) G1 gemm tiles (wait ctr1==4099).
// [4611,6915) att/write/out/mem transposes (no wait; consumed next dispatch).
// Capacity: LDS 48KB -> 3 blocks/CU = 768 resident; spinners 512 -> >=256 slots always
// flow productive blocks -> deadlock-free under any dispatch order.
__global__ __launch_bounds__(256, 2) void k_mega1(
        const float* __restrict__ x, bf16* __restrict__ xbf,
        const float* __restrict__ gw, const float* __restrict__ gb,
        const float* __restrict__ aw_in,
        float* __restrict__ gate, float* __restrict__ actw,
        const float* __restrict__ w_, bf16* __restrict__ wT,
        const float* __restrict__ att_w, const float* __restrict__ write_w,
        const float* __restrict__ out_w, bf16* __restrict__ catT,
        const float* __restrict__ mem, bf16* __restrict__ memT,
        float* __restrict__ zbase,
        const float* __restrict__ bias, bf16* __restrict__ hidden,
        const float* __restrict__ mask, unsigned* __restrict__ ctr1) {
    __shared__ __align__(16) SMemT<128> sm;
    int bid = blockIdx.x, t = threadIdx.x;
    if (bid < 4099) {
        if (bid < 2048) {
            do_transpose(w_, wT, 1024, 8192, bid & 127, bid >> 7, t, sm.tr);
        } else if (bid < 3072) {
            int i = (bid - 2048)*256 + t;
            f32x4 v = ((const f32x4*)x)[i];
            s16x4 o;
            #pragma unroll
            for (int j = 0; j < 4; j++) o[j] = f2bf_s(v[j]);
            ((s16x4*)xbf)[i] = o;
            if (bid == 2048 && t == 64) {
                float a[9]; float m = -1e30f;
                for (int i2 = 0; i2 < 9; i2++) { a[i2] = aw_in[i2]; m = fmaxf(m, a[i2]); }
                float ss = 0.f;
                for (int i2 = 0; i2 < 9; i2++) { a[i2] = __expf(a[i2]-m); ss += a[i2]; }
                float inv = 1.f / ss;
                for (int i2 = 0; i2 < 9; i2++) actw[i2] = a[i2]*inv;
            }
        } else if (bid < 4096) {
            int b = bid - 3072, w = t >> 6, lane = t & 63;
            float* l = (float*)&sm;   // overlay 4 floats
            float s = 0.f;
            for (int k = lane; k < 1024; k += 64)
                s += x[(size_t)b*1024 + k] * gw[k*4 + w];
            #pragma unroll
            for (int off = 32; off; off >>= 1) s += __shfl_xor(s, off);
            if (lane == 0) l[w] = s + gb[w];
            __syncthreads();
            if (t == 0) {
                float m = fmaxf(fmaxf(l[0], l[1]), fmaxf(l[2], l[3]));
                float e0 = __expf(l[0]-m), e1 = __expf(l[1]-m), e2 = __expf(l[2]-m), e3 = __expf(l[3]-m);
                float inv = 1.f / (e0+e1+e2+e3);
                gate[b*4+0] = e0*inv; gate[b*4+1] = e1*inv;
                gate[b*4+2] = e2*inv; gate[b*4+3] = e3*inv;
            }
        } else {
            int idx = (bid - 4096)*256 + t;       // zero 768 f32x4 = uvec+cmean
            ((f32x4*)zbase)[idx] = (f32x4){0.f, 0.f, 0.f, 0.f};
        }
        bump_ctr(ctr1);
    } else if (bid < 4611) {
        int c = bid - 4099;                        // 512 G1 gemm tiles
        wait_ctr(ctr1, 4099u);
        gemm_core<4, 128>(c & 63, c >> 6, 0, sm, xbf, wT, 1024, 1024, 1024, 0,
                          bias, nullptr, nullptr, nullptr, nullptr, hidden, nullptr,
                          gate, actw, mask, 2048);
    } else {
        int rel = bid - 4611;                      // 2304 transposes for G234/G5
        if (rel < 1024) {
            do_transpose(att_w, catT, 2048, 2048, rel & 31, rel >> 5, t, sm.tr);
        } else if (rel < 1536) {
            rel -= 1024;
            do_transpose(write_w, catT + 2048ull*2048, 2048, 1024, rel & 15, rel >> 4, t, sm.tr);
        } else if (rel < 1792) {
            rel -= 1536;
            do_transpose(out_w, catT + 3072ull*2048, 2048, 512, rel & 7, rel >> 3, t, sm.tr);
        } else {
            rel -= 1792;
            do_transpose(mem, memT, 2048, 1024, rel & 15, rel >> 4, t, sm.tr);
        }
    }
}

// ---------------- softmax one row of 2048 (red = 8-float LDS overlay) ----------------
__device__ __forceinline__ void softmax_row(bf16* __restrict__ row, int t, float* red) {
    int w = t >> 6, lane = t & 63;
    __syncthreads();                 // red reuse across rows
    float v[8];
    float mx = -1e30f;
    #pragma unroll
    for (int j = 0; j < 8; j++) {
        v[j] = __bfloat162float(row[t + j*256]);
        mx = fmaxf(mx, v[j]);
    }
    #pragma unroll
    for (int off = 32; off; off >>= 1) mx = fmaxf(mx, __shfl_xor(mx, off));
    if (lane == 0) red[w] = mx;
    __syncthreads();
    mx = fmaxf(fmaxf(red[0], red[1]), fmaxf(red[2], red[3]));
    float s = 0.f;
    #pragma unroll
    for (int j = 0; j < 8; j++) { v[j] = __expf(v[j] - mx); s += v[j]; }
    #pragma unroll
    for (int off = 32; off; off >>= 1) s += __shfl_xor(s, off);
    if (lane == 0) red[4 + w] = s;
    __syncthreads();
    float inv = 1.f / (red[4] + red[5] + red[6] + red[7]);
    #pragma unroll
    for (int j = 0; j < 8; j++)
        row[t + j*256] = __float2bfloat16(v[j] * inv);
}

// ================= MEGA 2: G234 gemm (counted) + softmax (spin, 512 blocks x 2 rows) =================
// Capacity: LDS 36KB -> 4/CU = 1024 resident; spinners 512.
__global__ __launch_bounds__(256, 2) void k_mega2(
        const bf16* __restrict__ hidden, const bf16* __restrict__ catT,
        const float* __restrict__ att_b, const float* __restrict__ write_b,
        const float* __restrict__ out_b,
        float* __restrict__ preds, bf16* __restrict__ ratt, bf16* __restrict__ cand,
        unsigned* __restrict__ ctr2) {
    __shared__ __align__(16) SMemT<64> sm;
    int bid = blockIdx.x, t = threadIdx.x;
    if (bid < 448) {
        gemm_core<5, 64>(bid % 28, bid / 28, 0, sm, hidden, catT, 2048, 2048, 2048, 0,
                         att_b, write_b, out_b, preds, nullptr, ratt, cand,
                         nullptr, nullptr, nullptr, 0);
        bump_ctr(ctr2);
    } else {
        wait_ctr(ctr2, 448u);
        int r0 = (bid - 448)*2;
        float* red = (float*)&sm;
        softmax_row(ratt + (size_t)r0*2048, t, red);
        softmax_row(ratt + (size_t)(r0 + 1)*2048, t, red);
    }
}

// ================= MEGA 3: G5 gemm + colpart (counted) + critic/newmem (spin) =================
// Block map: [0,512) G5 split-K gemm; [512,608) colpart-atomic; [608,1120) critic (2 rows);
// [1120,1376) newmem (2048 f32x4 each). Capacity 1024 @36KB; spinners 768.
__global__ __launch_bounds__(256, 2) void k_mega3(
        const bf16* __restrict__ ratt, const bf16* __restrict__ memT,
        const bf16* __restrict__ cand,
        float* __restrict__ readv, float* __restrict__ readv2,
        const float* __restrict__ update_gate,
        float* __restrict__ u, float* __restrict__ cmean,
        const float* __restrict__ preds, const bf16* __restrict__ hidden,
        const float* cw1, const float* cb1, const float* cw2, const float* cb2,
        const float* cw3, const float* cb3, const float* cw4, const float* cb4,
        const float* cw5, const float* cb5, const float* thr,
        float* __restrict__ out0,
        const float* __restrict__ mem, float* __restrict__ out1,
        unsigned* __restrict__ ctr3) {
    struct CriticSM {
        float sx[2*1024];
        float sp[2*512];
        short sh[2*2048];
        f32x4 part[2][32][8];
        float feat[2][96];
        float fused[2][64];
        float gsh[2];
    };
    __shared__ __align__(16) union { SMemT<64> g; CriticSM c; } sm;
    int bid = blockIdx.x, t = threadIdx.x;
    if (bid < 512) {
        int bx = bid & 7, by = (bid >> 3) & 15, bz = bid >> 7;
        gemm_core<3, 64>(bx, by, bz, sm.g, ratt, memT, 512, 2048, 2048, 512,
                         nullptr, nullptr, nullptr, readv, readv2, nullptr, nullptr,
                         nullptr, nullptr, nullptr, 1024);
        bump_ctr(ctr3);
        return;
    }
    if (bid < 608) {
        int rel = bid - 512;                       // 96 colpart blocks: 12 x 8
        int ct = rel % 12, rc = rel / 12;
        int col = ct*256 + t;
        const bf16* src; int stride, c;
        if (ct < 8) { src = ratt; stride = 2048; c = col; }
        else        { src = cand; stride = 1024; c = col - 2048; }
        float s = 0.f;
        int r0 = rc*128;
        for (int r2 = 0; r2 < 128; r2++)
            s += __bfloat162float(src[(size_t)(r0 + r2)*stride + c]);
        if (ct < 8) atomicAdd(&u[col], s * (update_gate[col] * (1.f/1024.f)));
        else        atomicAdd(&cmean[col - 2048], s * (1.f/1024.f));
        bump_ctr(ctr3);
        return;
    }
    wait_ctr(ctr3, 608u);
    if (bid >= 1120) {
        // new_mem blend, f32x4-vectorized: 256 blocks x 2048 f32x4
        int nb = bid - 1120;
        #pragma unroll
        for (int i = 0; i < 8; i++) {
            int idx = nb*2048 + i*256 + t;
            int m = idx >> 8, d4 = idx & 255;
            float um = u[m];
            f32x4 m4 = ((const f32x4*)mem)[idx];
            f32x4 c4 = ((const f32x4*)cmean)[d4];
            f32x4 o;
            #pragma unroll
            for (int j = 0; j < 4; j++) o[j] = m4[j] * (1.f - um) + um * c4[j];
            ((f32x4*)out1)[idx] = o;
        }
        return;
    }
    // critic: 2 rows/block
    int b0 = (bid - 608) * 2;
    int j4 = t & 7, kg = t >> 3;
    {
        const f32x4* r0 = (const f32x4*)(readv  + (size_t)b0*1024);
        const f32x4* r1 = (const f32x4*)(readv2 + (size_t)b0*1024);
        const f32x4* r2 = (const f32x4*)(readv2 + 1048576 + (size_t)b0*1024);
        const f32x4* r3 = (const f32x4*)(readv2 + 2097152 + (size_t)b0*1024);
        ((f32x4*)sm.c.sx)[t]       = r0[t] + r1[t] + r2[t] + r3[t];
        ((f32x4*)sm.c.sx)[t + 256] = r0[t + 256] + r1[t + 256] + r2[t + 256] + r3[t + 256];
    }
    ((f32x4*)sm.c.sp)[t]       = ((const f32x4*)(preds + (size_t)b0*512))[t];
    ((s16x8*)sm.c.sh)[t]       = ((const s16x8*)(hidden + (size_t)b0*2048))[t];
    ((s16x8*)sm.c.sh)[t + 256] = ((const s16x8*)(hidden + (size_t)b0*2048))[t + 256];
    __syncthreads();
    {
        const f32x4* wv = (const f32x4*)cw1;
        f32x4 a0 = (f32x4){0,0,0,0}, a1 = (f32x4){0,0,0,0};
        int k0 = kg*32;
        #pragma unroll 4
        for (int k = k0; k < k0 + 32; k++) {
            f32x4 wq = wv[k*8 + j4];
            a0 += sm.c.sx[k] * wq;
            a1 += sm.c.sx[1024 + k] * wq;
        }
        sm.c.part[0][kg][j4] = a0; sm.c.part[1][kg][j4] = a1;
    }
    __syncthreads();
    if (t < 64) {
        int r = t >> 5, f = t & 31;
        float s = 0.f;
        #pragma unroll
        for (int i = 0; i < 32; i++) s += sm.c.part[r][i][f >> 2][f & 3];
        sm.c.feat[r][f] = fmaxf(s + cb1[f], 0.f);
    }
    __syncthreads();
    {
        const f32x4* wv = (const f32x4*)cw2;
        f32x4 a0 = (f32x4){0,0,0,0}, a1 = (f32x4){0,0,0,0};
        int k0 = kg*16;
        #pragma unroll 4
        for (int k = k0; k < k0 + 16; k++) {
            f32x4 wq = wv[k*8 + j4];
            a0 += sm.c.sp[k] * wq;
            a1 += sm.c.sp[512 + k] * wq;
        }
        sm.c.part[0][kg][j4] = a0; sm.c.part[1][kg][j4] = a1;
    }
    __syncthreads();
    if (t < 64) {
        int r = t >> 5, f = t & 31;
        float s = 0.f;
        #pragma unroll
        for (int i = 0; i < 32; i++) s += sm.c.part[r][i][f >> 2][f & 3];
        sm.c.feat[r][32 + f] = fmaxf(s + cb2[f], 0.f);
    }
    __syncthreads();
    {
        const f32x4* wv = (const f32x4*)cw3;
        f32x4 a0 = (f32x4){0,0,0,0}, a1 = (f32x4){0,0,0,0};
        int k0 = kg*64;
        #pragma unroll 4
        for (int k = k0; k < k0 + 64; k++) {
            f32x4 wq = wv[k*8 + j4];
            float h0 = __bfloat162float(*reinterpret_cast<const bf16*>(&sm.c.sh[k]));
            float h1 = __bfloat162float(*reinterpret_cast<const bf16*>(&sm.c.sh[2048 + k]));
            a0 += h0 * wq;
            a1 += h1 * wq;
        }
        sm.c.part[0][kg][j4] = a0; sm.c.part[1][kg][j4] = a1;
    }
    __syncthreads();
    if (t < 64) {
        int r = t >> 5, f = t & 31;
        float s = 0.f;
        #pragma unroll
        for (int i = 0; i < 32; i++) s += sm.c.part[r][i][f >> 2][f & 3];
        sm.c.feat[r][64 + f] = fmaxf(s + cb3[f], 0.f);
    }
    __syncthreads();
    if (t < 128) {
        int r = t >> 6, uu = t & 63;
        float s = 0.f;
        #pragma unroll 8
        for (int k = 0; k < 96; k++) s += sm.c.feat[r][k] * cw4[k*64 + uu];
        sm.c.fused[r][uu] = fmaxf(s + cb4[uu], 0.f);
    }
    __syncthreads();
    if (t < 128) {
        int r = t >> 6, lane = t & 63;
        float v = sm.c.fused[r][lane] * cw5[lane*2];
        #pragma unroll
        for (int off = 32; off; off >>= 1) v += __shfl_xor(v, off);
        if (lane == 0)
            sm.c.gsh[r] = 1.f / (1.f + __expf(-(v + cb5[0] - thr[0])));
    }
    __syncthreads();
    #pragma unroll
    for (int idx = t; idx < 1024; idx += 256) {
        int r = idx >> 9, o = idx & 511;
        out0[(size_t)(b0 + r)*512 + o] = sm.c.sp[r*512 + o] * sm.c.gsh[r];
    }
}

extern "C" void kernel_launch(void* const* d_in, const int* in_sizes, int n_in,
                              void* d_out, int out_size, void* d_ws, size_t ws_size,
                              hipStream_t stream) {
    const float* x        = (const float*)d_in[0];
    const float* w_       = (const float*)d_in[1];
    const float* b_bias   = (const float*)d_in[2];
    const float* gate_w   = (const float*)d_in[3];
    const float* gate_b   = (const float*)d_in[4];
    const float* act_w    = (const float*)d_in[5];
    const float* mask     = (const float*)d_in[6];
    const float* mem      = (const float*)d_in[7];
    const float* att_w    = (const float*)d_in[8];
    const float* att_b    = (const float*)d_in[9];
    const float* write_w  = (const float*)d_in[10];
    const float* write_b  = (const float*)d_in[11];
    const float* upd_gate = (const float*)d_in[12];
    const float* out_w    = (const float*)d_in[13];
    const float* out_b    = (const float*)d_in[14];
    const float* cw1 = (const float*)d_in[15]; const float* cb1 = (const float*)d_in[16];
    const float* cw2 = (const float*)d_in[17]; const float* cb2 = (const float*)d_in[18];
    const float* cw3 = (const float*)d_in[19]; const float* cb3 = (const float*)d_in[20];
    const float* cw4 = (const float*)d_in[21]; const float* cb4 = (const float*)d_in[22];
    const float* cw5 = (const float*)d_in[23]; const float* cb5 = (const float*)d_in[24];
    const float* thr = (const float*)d_in[25];

    char* ws = (char*)d_ws;
    float* gate   = (float*)(ws + GATE_OFF);
    float* actw   = (float*)(ws + ACTW_OFF);
    float* uvec   = (float*)(ws + U_OFF);
    float* cmean  = (float*)(ws + CMEAN_OFF);
    bf16*  hidden = (bf16*)(ws + HIDDEN_OFF);
    bf16*  ratt   = (bf16*)(ws + RATT_OFF);
    bf16*  cand   = (bf16*)(ws + CAND_OFF);
    float* preds  = (float*)(ws + PREDS_OFF);
    float* readv  = (float*)(ws + READ_OFF);
    float* readv2 = (float*)(ws + READ2_OFF);   // aliases wT head (dead after G1): 3 partials
    bf16*  xbf    = (bf16*)(ws + XBF_OFF);
    bf16*  wT     = (bf16*)(ws + WT_OFF);
    bf16*  catT   = (bf16*)(ws + CATT_OFF);
    bf16*  memT   = (bf16*)(ws + MEMT_OFF);
    unsigned* ctrs = (unsigned*)(ws + CTR_OFF); // [0]=ctr1 [1]=ctr2 [2]=ctr3

    float* out0 = (float*)d_out;            // (1024, 512)
    float* out1 = out0 + 1024*512;          // (2048, 1024)

    // zero dependency counters (graph-capturable memset node)
    hipMemsetAsync(ctrs, 0, 256, stream);

    // MEGA 1: prepass + G1 + trailing transposes — 6915 blocks
    k_mega1<<<6915, 256, 0, stream>>>(x, xbf, gate_w, gate_b, act_w, gate, actw,
                                      w_, wT, att_w, write_w, out_w, catT, mem, memT,
                                      uvec, b_bias, hidden, mask, ctrs + 0);

    // MEGA 2: G234 heads + softmax — 960 blocks
    k_mega2<<<960, 256, 0, stream>>>(hidden, catT, att_b, write_b, out_b,
                                     preds, ratt, cand, ctrs + 1);

    // MEGA 3: G5 split-K + colpart + critic + newmem — 1376 blocks
    k_mega3<<<1376, 256, 0, stream>>>(ratt, memT, cand, readv, readv2, upd_gate,
                                      uvec, cmean, preds, hidden,
                                      cw1, cb1, cw2, cb2, cw3, cb3, cw4, cb4, cw5, cb5,
                                      thr, out0, mem, out1, ctrs + 2);
}

// Round 7
// 258.853 us; speedup vs baseline: 2.2511x; 2.2511x over previous
//
#include <hip/hip_runtime.h>
#include <hip/hip_bf16.h>
#include <math.h>

typedef __attribute__((ext_vector_type(4))) float f32x4;
typedef __attribute__((ext_vector_type(2))) float f32x2;
typedef __attribute__((ext_vector_type(8))) short s16x8;
typedef __attribute__((ext_vector_type(4))) short s16x4;
typedef __hip_bfloat16 bf16;

#define MB (1024ull*1024ull)
// workspace layout (bytes) — total 53 MB
#define GATE_OFF    (0ull)
#define ACTW_OFF    (16ull*1024)
#define U_OFF       (20ull*1024)
#define CMEAN_OFF   (28ull*1024)
#define PART_OFF    (64ull*1024)
#define HIDDEN_OFF  (1ull*MB)
#define RATT_OFF    (5ull*MB)
#define CAND_OFF    (9ull*MB)
#define PREDS_OFF   (11ull*MB)
#define READ_OFF    (13ull*MB)
#define XBF_OFF     (17ull*MB)
#define WT_OFF      (19ull*MB)      // bf16 8192x1024 (16MB); G5 partials alias head after G1
#define CATT_OFF    (35ull*MB)      // bf16 3584x2048 (14MB)
#define MEMT_OFF    (49ull*MB)      // bf16 1024x2048 (4MB)
#define READ2_OFF   WT_OFF

__device__ __forceinline__ short f2bf_s(float f) {
    bf16 h = __float2bfloat16(f);
    return *reinterpret_cast<short*>(&h);
}

__device__ __forceinline__ void async_load16(const bf16* g, short* l) {
    __builtin_amdgcn_global_load_lds((const __attribute__((address_space(1))) void*)g,
                                     (__attribute__((address_space(3))) void*)l, 16, 0, 0);
}

__device__ __forceinline__ float fast_tanh(float x) {
    float e2x = __expf(2.f * x);
    return 1.f - 2.f / (e2x + 1.f);
}

// fast 9-way activation mix — __expf algebra only (validated round 9)
__device__ __forceinline__ float qact(float x, const float* w) {
    float ex  = __expf(x);
    float r1  = 1.f / (1.f + ex);
    float sig = 1.f - r1;
    float em1 = ex - 1.f;
    float elu = x > 0.f ? x : em1;
    float e2x = ex * ex;
    float th  = 1.f - 2.f / (e2x + 1.f);
    float rel = fmaxf(x, 0.f);
    float silu = x * sig;
    float u   = 0.7978845608028654f * (x + 0.044715f * x * x * x);
    float e2u = __expf(2.f * u);
    float gel = x * (1.f - 1.f / (e2u + 1.f));
    float sel = 1.0507009873554805f * (x > 0.f ? x : 1.6732632423543772f * em1);
    float t   = 1.f + ex;
    float t2  = t * t;
    float mish = x * (1.f - 2.f / (t2 + 1.f));
    return w[0]*sig + w[1]*elu + w[2]*th + w[3]*rel + w[4]*silu
         + w[5]*gel + w[6]*sel + w[7]*mish + w[8]*x;
}

// ---------------- 64x64 f32 -> bf16 transpose tile (f32x2 loads; scratch 64x66 shorts) ----------------
__device__ __forceinline__ void do_transpose(const float* __restrict__ in,
                                             bf16* __restrict__ out, int R, int C,
                                             int bx, int by, int t, short* tile) {
    int k0 = by*64, n0 = bx*64;
    int i = t & 31, half = t >> 5;            // half = 0..7 over 256 threads
    #pragma unroll
    for (int r = 0; r < 8; r++) {
        int k = half + r*8;
        f32x2 v = *reinterpret_cast<const f32x2*>(&in[(size_t)(k0 + k)*C + n0 + i*2]);
        tile[(i*2 + 0)*66 + k] = f2bf_s(v[0]);
        tile[(i*2 + 1)*66 + k] = f2bf_s(v[1]);
    }
    __syncthreads();
    int kp = t & 31, nrow = t >> 5;
    #pragma unroll
    for (int jj = 0; jj < 8; jj++) {
        int n = nrow + jj*8;
        unsigned lo = (unsigned short)tile[n*66 + kp*2];
        unsigned hi = (unsigned short)tile[n*66 + kp*2 + 1];
        *reinterpret_cast<unsigned*>(&out[(size_t)(n0 + n)*R + k0 + kp*2]) = lo | (hi << 16);
    }
}

// ---------------- fused prepass: cvt+gate (fused, round 18) + wT transpose ----------------
// Round 18: gate dot-product fused into the cvt block — block b already holds x row b in
// registers (f32x4 per thread), so the 4 branch-gate logits are computed from those same
// registers with L2-hot f32x4 gw row loads. Eliminates 1024 gate blocks and the 4MB
// stride-scalar re-read of x. Block map: [0,1024) cvt+gate; [1024,3072) wT transpose.
__global__ __launch_bounds__(256) void k_prepass(
        const float* __restrict__ x, bf16* __restrict__ xbf,
        const float* __restrict__ gw, const float* __restrict__ gb,
        const float* __restrict__ aw_in,
        float* __restrict__ gate, float* __restrict__ actw,
        const float* __restrict__ w_, bf16* __restrict__ wT) {
    __shared__ short tile[64*66];
    int blk = blockIdx.x, t = threadIdx.x;
    if (blk < 1024) {
        int b = blk;                       // this block owns x row b
        f32x4 v = ((const f32x4*)x)[b*256 + t];
        s16x4 o;
        #pragma unroll
        for (int j = 0; j < 4; j++) o[j] = f2bf_s(v[j]);
        ((s16x4*)xbf)[b*256 + t] = o;
        // gate logits from the same registers: k = 4t+j
        const f32x4* gwv = (const f32x4*)gw;      // gw row i = all 4 branch weights for k=i
        f32x4 a = v[0] * gwv[4*t + 0];
        a += v[1] * gwv[4*t + 1];
        a += v[2] * gwv[4*t + 2];
        a += v[3] * gwv[4*t + 3];
        #pragma unroll
        for (int off = 32; off; off >>= 1) {
            #pragma unroll
            for (int j = 0; j < 4; j++) a[j] += __shfl_xor(a[j], off);
        }
        float* red = (float*)tile;
        int w = t >> 6, lane = t & 63;
        if (lane == 0) *reinterpret_cast<f32x4*>(&red[w*4]) = a;
        __syncthreads();
        if (t == 0) {
            f32x4 s = *reinterpret_cast<f32x4*>(&red[0]);
            s += *reinterpret_cast<f32x4*>(&red[4]);
            s += *reinterpret_cast<f32x4*>(&red[8]);
            s += *reinterpret_cast<f32x4*>(&red[12]);
            float l0 = s[0] + gb[0], l1 = s[1] + gb[1], l2 = s[2] + gb[2], l3 = s[3] + gb[3];
            float m = fmaxf(fmaxf(l0, l1), fmaxf(l2, l3));
            float e0 = __expf(l0-m), e1 = __expf(l1-m), e2 = __expf(l2-m), e3 = __expf(l3-m);
            float inv = 1.f / (e0+e1+e2+e3);
            gate[b*4+0] = e0*inv; gate[b*4+1] = e1*inv;
            gate[b*4+2] = e2*inv; gate[b*4+3] = e3*inv;
        }
        // act-weight softmax (once; touches no shared state)
        if (blk == 0 && t == 64) {
            float aa[9]; float m = -1e30f;
            for (int i2 = 0; i2 < 9; i2++) { aa[i2] = aw_in[i2]; m = fmaxf(m, aa[i2]); }
            float ss = 0.f;
            for (int i2 = 0; i2 < 9; i2++) { aa[i2] = __expf(aa[i2]-m); ss += aa[i2]; }
            float inv = 1.f / ss;
            for (int i2 = 0; i2 < 9; i2++) actw[i2] = aa[i2]*inv;
        }
    } else {
        int rel = blk - 1024;                       // w_: 1024x8192, gridX=128
        do_transpose(w_, wT, 1024, 8192, rel & 127, rel >> 7, t, tile);
    }
}

// ---------------- GEMM (BT): C = A(MxK) @ Bt(NxK)^T, TMx128 tile, BK=32 ----------------
// Round 15: LDS k-slot XOR swizzle (SQ_LDS_BANK_CONFLICT 2.36M -> 262K, verified).
// Round 16: triple-buffered K-loop, counted vmcnt (never 0 mid-loop), raw s_barrier.
template <int TM>
union SMemT {
    struct { short a[3][TM*32]; short b[3][128*32]; } tl;
    float z[TM*32];
    short tr[64*66];
};

template <int MODE, int TM>
__device__ __forceinline__ void gemm_core(
        int bx, int by, int bz, SMemT<TM>& sm,
        const bf16* __restrict__ A, const bf16* __restrict__ Bt,
        int K, int lda, int ldb, int kOffset,
        const float* __restrict__ bias, const float* __restrict__ bias2,
        const float* __restrict__ bias3,
        float* __restrict__ outF, float* __restrict__ outF2,
        bf16* __restrict__ outH, bf16* __restrict__ outH2,
        const float* __restrict__ gate, const float* __restrict__ actw,
        const float* __restrict__ mask, int outStride) {
    constexpr int MI = TM / 32;
    int t = threadIdx.x, lane = t & 63;
    int rowBase = by * TM, colBase = bx * 128;
    int lm = lane & 15, lq = lane >> 4;
    int w = t >> 6;
    int qm = (w >> 1) * (TM/2), qn = (w & 1) * 64;

    A  += (size_t)kOffset * bz;
    Bt += (size_t)kOffset * bz;

    f32x4 acc[MI][4];
    #pragma unroll
    for (int i = 0; i < MI; i++)
        #pragma unroll
        for (int j = 0; j < 4; j++) acc[i][j] = (f32x4){0.f, 0.f, 0.f, 0.f};

    // B staging: chunks c = w*128 + lane (+64); source k pre-swizzled: s' = s ^ ((row>>1)&3)
    int cb0 = w*128 + lane, cb1 = cb0 + 64;
    int rb0 = cb0 >> 2, kb0 = ((cb0 & 3) ^ ((rb0 >> 1) & 3)) * 8;
    int rb1 = cb1 >> 2, kb1 = ((cb1 & 3) ^ ((rb1 >> 1) & 3)) * 8;
    // A staging
    int ca0 = (TM == 128) ? (w*128 + lane) : (w*64 + lane);
    int ra0 = ca0 >> 2, ka0 = ((ca0 & 3) ^ ((ra0 >> 1) & 3)) * 8;
    int ca1 = ca0 + 64;
    int ra1 = ca1 >> 2, ka1 = ((ca1 & 3) ^ ((ra1 >> 1) & 3)) * 8;   // TM=128 only

    auto issueLoads = [&](int k0, int ib) {
        short* bA = sm.tl.a[ib];
        short* bB = sm.tl.b[ib];
        async_load16(A + (size_t)(rowBase + ra0)*lda + k0 + ka0,
                     bA + ((TM == 128) ? w*1024 : w*512));
        if (TM == 128)
            async_load16(A + (size_t)(rowBase + ra1)*lda + k0 + ka1, bA + w*1024 + 512);
        async_load16(Bt + (size_t)(colBase + rb0)*ldb + k0 + kb0, bB + w*1024);
        async_load16(Bt + (size_t)(colBase + rb1)*ldb + k0 + kb1, bB + w*1024 + 512);
    };

    issueLoads(0, 0);
    if (32 < K) issueLoads(32, 1);
    int ib = 0;
    for (int k0 = 0; k0 < K; k0 += 32) {
        // wait for THIS step's loads only; k+1/k+2 stay in flight across the barrier (T4)
        if (k0 + 32 < K) {
            if (TM == 128) asm volatile("s_waitcnt vmcnt(4)" ::: "memory");
            else           asm volatile("s_waitcnt vmcnt(3)" ::: "memory");
        } else {
            asm volatile("s_waitcnt vmcnt(0)" ::: "memory");
        }
        __builtin_amdgcn_sched_barrier(0);
        __builtin_amdgcn_s_barrier();
        __builtin_amdgcn_sched_barrier(0);
        int ibn = ib + 2; if (ibn >= 3) ibn -= 3;
        if (k0 + 64 < K) issueLoads(k0 + 64, ibn);
        const short* cA = sm.tl.a[ib];
        const short* cB = sm.tl.b[ib];
        s16x8 af[MI], bfr[4];
        #pragma unroll
        for (int mi = 0; mi < MI; mi++) {
            int r = qm + mi*16 + lm;
            af[mi] = *reinterpret_cast<const s16x8*>(cA + r*32 + ((lq ^ ((r >> 1) & 3)) * 8));
        }
        #pragma unroll
        for (int ni = 0; ni < 4; ni++) {
            int r = qn + ni*16 + lm;
            bfr[ni] = *reinterpret_cast<const s16x8*>(cB + r*32 + ((lq ^ ((r >> 1) & 3)) * 8));
        }
        #pragma unroll
        for (int mi = 0; mi < MI; mi++)
            #pragma unroll
            for (int ni = 0; ni < 4; ni++)
                acc[mi][ni] = __builtin_amdgcn_mfma_f32_16x16x32_bf16(af[mi], bfr[ni], acc[mi][ni], 0, 0, 0);
        ib += 1; if (ib >= 3) ib = 0;
    }

    if (MODE == 4) {
        __syncthreads();   // all tile reads done; safe to overlay sm.z
        #pragma unroll
        for (int mi = 0; mi < MI; mi++) {
            int rowl0 = qm + mi*16 + lq*4;
            #pragma unroll
            for (int ni = 0; ni < 4; ni++) {
                int col = colBase + qn + ni*16 + lm;
                int n = col & 3;
                float bb = bias[col];
                f32x4 v = acc[mi][ni];
                #pragma unroll
                for (int r = 0; r < 4; r++) v[r] = (v[r] + bb) * gate[(rowBase + rowl0 + r)*4 + n];
                #pragma unroll
                for (int r = 0; r < 4; r++) v[r] += __shfl_xor(v[r], 1);
                #pragma unroll
                for (int r = 0; r < 4; r++) v[r] += __shfl_xor(v[r], 2);
                if ((lane & 3) == 0) {
                    int ul = ((w & 1) << 4) + ni*4 + (lm >> 2);
                    #pragma unroll
                    for (int r = 0; r < 4; r++)
                        sm.z[(rowl0 + r)*32 + ul] = v[r];
                }
            }
        }
        __syncthreads();
        float aw[9];
        #pragma unroll
        for (int i = 0; i < 9; i++) aw[i] = actw[i];
        int u0 = colBase >> 2;
        #pragma unroll
        for (int i = 0; i < TM/8; i++) {
            int idx = t + i*256;
            int row = idx >> 5, ul = idx & 31;
            int ug = u0 + ul;
            float zz = sm.z[idx];
            outH[(size_t)(rowBase + row)*outStride + ug] = __float2bfloat16(qact(zz, aw) * mask[ug]);
        }
    } else if (MODE == 5) {
        #pragma unroll
        for (int mi = 0; mi < MI; mi++) {
            int row0 = rowBase + qm + mi*16 + lq*4;
            #pragma unroll
            for (int ni = 0; ni < 4; ni++) {
                int col = colBase + qn + ni*16 + lm;
                if (col < 2048) {
                    float bb = bias[col];
                    #pragma unroll
                    for (int r = 0; r < 4; r++)
                        outH[(size_t)(row0 + r)*2048 + col] = __float2bfloat16(acc[mi][ni][r] + bb);
                } else if (col < 3072) {
                    int c = col - 2048;
                    float bb = bias2[c];
                    #pragma unroll
                    for (int r = 0; r < 4; r++)
                        outH2[(size_t)(row0 + r)*1024 + c] = __float2bfloat16(fast_tanh(acc[mi][ni][r] + bb));
                } else {
                    int c = col - 3072;
                    float bb = bias3[c];
                    #pragma unroll
                    for (int r = 0; r < 4; r++)
                        outF[(size_t)(row0 + r)*512 + c] = acc[mi][ni][r] + bb;
                }
            }
        }
    } else {  // MODE 3 (split-K partial, z in [0,4): partial 0 -> outF, z>0 -> outF2 + (z-1)*1M floats)
        float* of = bz ? (outF2 + (size_t)(bz - 1) * 1048576) : outF;
        #pragma unroll
        for (int mi = 0; mi < MI; mi++) {
            int row0 = rowBase + qm + mi*16 + lq*4;
            #pragma unroll
            for (int ni = 0; ni < 4; ni++) {
                int col = colBase + qn + ni*16 + lm;
                #pragma unroll
                for (int r = 0; r < 4; r++)
                    of[(size_t)(row0 + r)*outStride + col] = acc[mi][ni][r];
            }
        }
    }
}

template <int MODE, int TM>
__global__ __launch_bounds__(256, 2) void gemm_bt(
        const bf16* __restrict__ A, const bf16* __restrict__ Bt,
        int K, int lda, int ldb, int kOffset,
        const float* __restrict__ bias, const float* __restrict__ bias2,
        const float* __restrict__ bias3,
        float* __restrict__ outF, float* __restrict__ outF2,
        bf16* __restrict__ outH, bf16* __restrict__ outH2,
        const float* __restrict__ gate, const float* __restrict__ actw,
        const float* __restrict__ mask, int outStride) {
    __shared__ __align__(16) SMemT<TM> sm;
    gemm_core<MODE, TM>(blockIdx.x, blockIdx.y, blockIdx.z, sm,
                        A, Bt, K, lda, ldb, kOffset, bias, bias2, bias3,
                        outF, outF2, outH, outH2, gate, actw, mask, outStride);
}

// ---------------- G1 fused dispatch: 512 gemm blocks (TM=128) + 2304 trailing transposes ----------------
// gemm blocks FIRST (full 2-block/CU residency from t=0; round-2 interleave and round-6
// spin-fusion both regressed); transposes backfill as gemm retires.
__global__ __launch_bounds__(256, 2) void k_g1x(
        const bf16* __restrict__ xbf, const bf16* __restrict__ wT,
        const float* __restrict__ bias, bf16* __restrict__ hidden,
        const float* __restrict__ gate, const float* __restrict__ actw,
        const float* __restrict__ mask,
        const float* __restrict__ att_w, const float* __restrict__ write_w,
        const float* __restrict__ out_w, bf16* __restrict__ catT,
        const float* __restrict__ mem, bf16* __restrict__ memT) {
    __shared__ __align__(16) SMemT<128> sm;
    int bid = blockIdx.x, t = threadIdx.x;
    if (bid < 512) {
        gemm_core<4, 128>(bid & 63, bid >> 6, 0, sm, xbf, wT, 1024, 1024, 1024, 0,
                          bias, nullptr, nullptr, nullptr, nullptr, hidden, nullptr,
                          gate, actw, mask, 2048);
    } else {
        int rel = bid - 512;
        if (rel < 1024) {
            do_transpose(att_w, catT, 2048, 2048, rel & 31, rel >> 5, t, sm.tr);
        } else if (rel < 1536) {
            rel -= 1024;
            do_transpose(write_w, catT + 2048ull*2048, 2048, 1024, rel & 15, rel >> 4, t, sm.tr);
        } else if (rel < 1792) {
            rel -= 1536;
            do_transpose(out_w, catT + 3072ull*2048, 2048, 512, rel & 7, rel >> 3, t, sm.tr);
        } else {
            rel -= 1792;
            do_transpose(mem, memT, 2048, 1024, rel & 15, rel >> 4, t, sm.tr);
        }
    }
}

// ---------------- in-place row softmax over 2048 cols (bf16 buffer) ----------------
__global__ __launch_bounds__(256) void k_softmax(bf16* __restrict__ ratt) {
    int b = blockIdx.x, t = threadIdx.x, w = t >> 6, lane = t & 63;
    __shared__ float red[8];
    bf16* row = ratt + (size_t)b*2048;
    float v[8];
    float mx = -1e30f;
    #pragma unroll
    for (int j = 0; j < 8; j++) {
        v[j] = __bfloat162float(row[t + j*256]);
        mx = fmaxf(mx, v[j]);
    }
    #pragma unroll
    for (int off = 32; off; off >>= 1) mx = fmaxf(mx, __shfl_xor(mx, off));
    if (lane == 0) red[w] = mx;
    __syncthreads();
    mx = fmaxf(fmaxf(red[0], red[1]), fmaxf(red[2], red[3]));
    float s = 0.f;
    #pragma unroll
    for (int j = 0; j < 8; j++) { v[j] = __expf(v[j] - mx); s += v[j]; }
    #pragma unroll
    for (int off = 32; off; off >>= 1) s += __shfl_xor(s, off);
    if (lane == 0) red[4 + w] = s;
    __syncthreads();
    float inv = 1.f / (red[4] + red[5] + red[6] + red[7]);
    #pragma unroll
    for (int j = 0; j < 8; j++)
        row[t + j*256] = __float2bfloat16(v[j] * inv);
}

// ---------------- G5 fused dispatch: split-K read GEMM (512 blocks) + colpart (96 trailing) ----------------
__global__ __launch_bounds__(256, 2) void k_g5x(
        const bf16* __restrict__ ratt, const bf16* __restrict__ memT,
        const bf16* __restrict__ cand,
        float* __restrict__ readv, float* __restrict__ readv2,
        float* __restrict__ part) {
    __shared__ __align__(16) SMemT<64> sm;
    int bid = blockIdx.x, t = threadIdx.x;
    if (bid < 512) {
        int bx = bid & 7, by = (bid >> 3) & 15, bz = bid >> 7;
        gemm_core<3, 64>(bx, by, bz, sm, ratt, memT, 512, 2048, 2048, 512,
                         nullptr, nullptr, nullptr, readv, readv2, nullptr, nullptr,
                         nullptr, nullptr, nullptr, 1024);
    } else {
        int rel = bid - 512;                       // 96 colpart blocks: 12 x 8
        int ct = rel % 12, rc = rel / 12;
        int col = ct*256 + t;
        const bf16* src; int stride, c;
        if (ct < 8) { src = ratt; stride = 2048; c = col; }
        else        { src = cand; stride = 1024; c = col - 2048; }
        float s = 0.f;
        int r0 = rc*128;
        for (int r2 = 0; r2 < 128; r2++)
            s += __bfloat162float(src[(size_t)(r0 + r2)*stride + c]);
        part[rc*3072 + col] = s;
    }
}

__global__ __launch_bounds__(256) void k_colfin(const float* __restrict__ part,
                                                const float* __restrict__ update_gate,
                                                float* __restrict__ u,
                                                float* __restrict__ cmean) {
    int col = blockIdx.x*256 + threadIdx.x;
    float s = 0.f;
    #pragma unroll
    for (int rc = 0; rc < 8; rc++) s += part[rc*3072 + col];
    s *= (1.f/1024.f);
    if (col < 2048) u[col] = s * update_gate[col];
    else            cmean[col - 2048] = s;
}

// ---------------- final fused dispatch: critic (512 blocks) + vectorized newmem (2048 blocks) ----------------
// critic: 2 rows/block, f32x4 weight loads (round-10 validated); sums 4 split-K read partials.
__global__ __launch_bounds__(256) void k_fin(
        const float* __restrict__ readv, const float* __restrict__ readv2,
        const float* __restrict__ preds, const bf16* __restrict__ hidden,
        const float* cw1, const float* cb1, const float* cw2, const float* cb2,
        const float* cw3, const float* cb3, const float* cw4, const float* cb4,
        const float* cw5, const float* cb5, const float* thr,
        float* __restrict__ out0,
        const float* __restrict__ mem, const float* __restrict__ u,
        const float* __restrict__ cmean, float* __restrict__ out1) {
    __shared__ __align__(16) float sx[2*1024];
    __shared__ __align__(16) float sp[2*512];
    __shared__ __align__(16) short sh[2*2048];
    __shared__ __align__(16) f32x4 part[2][32][8];
    __shared__ float feat[2][96];
    __shared__ float fused[2][64];
    __shared__ float gsh[2];
    int bid = blockIdx.x, t = threadIdx.x;
    if (bid >= 512) {
        // new_mem blend, f32x4-vectorized: idx over 2048x1024 f32 in groups of 4
        int idx = (bid - 512)*256 + t;             // f32x4 index, 524288 total
        int m = idx >> 8, d4 = idx & 255;
        float um = u[m];
        f32x4 m4 = ((const f32x4*)mem)[idx];
        f32x4 c4 = ((const f32x4*)cmean)[d4];
        f32x4 o;
        #pragma unroll
        for (int j = 0; j < 4; j++) o[j] = m4[j] * (1.f - um) + um * c4[j];
        ((f32x4*)out1)[idx] = o;
        return;
    }
    int b0 = bid * 2;
    int j4 = t & 7, kg = t >> 3;

    {
        const f32x4* r0 = (const f32x4*)(readv  + (size_t)b0*1024);
        const f32x4* r1 = (const f32x4*)(readv2 + (size_t)b0*1024);
        const f32x4* r2 = (const f32x4*)(readv2 + 1048576 + (size_t)b0*1024);
        const f32x4* r3 = (const f32x4*)(readv2 + 2097152 + (size_t)b0*1024);
        ((f32x4*)sx)[t]       = r0[t] + r1[t] + r2[t] + r3[t];
        ((f32x4*)sx)[t + 256] = r0[t + 256] + r1[t + 256] + r2[t + 256] + r3[t + 256];
    }
    ((f32x4*)sp)[t]       = ((const f32x4*)(preds + (size_t)b0*512))[t];
    ((s16x8*)sh)[t]       = ((const s16x8*)(hidden + (size_t)b0*2048))[t];
    ((s16x8*)sh)[t + 256] = ((const s16x8*)(hidden + (size_t)b0*2048))[t + 256];
    __syncthreads();

    {
        const f32x4* wv = (const f32x4*)cw1;
        f32x4 a0 = (f32x4){0,0,0,0}, a1 = (f32x4){0,0,0,0};
        int k0 = kg*32;
        #pragma unroll 4
        for (int k = k0; k < k0 + 32; k++) {
            f32x4 wq = wv[k*8 + j4];
            a0 += sx[k] * wq;
            a1 += sx[1024 + k] * wq;
        }
        part[0][kg][j4] = a0; part[1][kg][j4] = a1;
    }
    __syncthreads();
    if (t < 64) {
        int r = t >> 5, f = t & 31;
        float s = 0.f;
        #pragma unroll
        for (int i = 0; i < 32; i++) s += part[r][i][f >> 2][f & 3];
        feat[r][f] = fmaxf(s + cb1[f], 0.f);
    }
    __syncthreads();
    {
        const f32x4* wv = (const f32x4*)cw2;
        f32x4 a0 = (f32x4){0,0,0,0}, a1 = (f32x4){0,0,0,0};
        int k0 = kg*16;
        #pragma unroll 4
        for (int k = k0; k < k0 + 16; k++) {
            f32x4 wq = wv[k*8 + j4];
            a0 += sp[k] * wq;
            a1 += sp[512 + k] * wq;
        }
        part[0][kg][j4] = a0; part[1][kg][j4] = a1;
    }
    __syncthreads();
    if (t < 64) {
        int r = t >> 5, f = t & 31;
        float s = 0.f;
        #pragma unroll
        for (int i = 0; i < 32; i++) s += part[r][i][f >> 2][f & 3];
        feat[r][32 + f] = fmaxf(s + cb2[f], 0.f);
    }
    __syncthreads();
    {
        const f32x4* wv = (const f32x4*)cw3;
        f32x4 a0 = (f32x4){0,0,0,0}, a1 = (f32x4){0,0,0,0};
        int k0 = kg*64;
        #pragma unroll 4
        for (int k = k0; k < k0 + 64; k++) {
            f32x4 wq = wv[k*8 + j4];
            float h0 = __bfloat162float(*reinterpret_cast<const bf16*>(&sh[k]));
            float h1 = __bfloat162float(*reinterpret_cast<const bf16*>(&sh[2048 + k]));
            a0 += h0 * wq;
            a1 += h1 * wq;
        }
        part[0][kg][j4] = a0; part[1][kg][j4] = a1;
    }
    __syncthreads();
    if (t < 64) {
        int r = t >> 5, f = t & 31;
        float s = 0.f;
        #pragma unroll
        for (int i = 0; i < 32; i++) s += part[r][i][f >> 2][f & 3];
        feat[r][64 + f] = fmaxf(s + cb3[f], 0.f);
    }
    __syncthreads();
    if (t < 128) {
        int r = t >> 6, uu = t & 63;
        float s = 0.f;
        #pragma unroll 8
        for (int k = 0; k < 96; k++) s += feat[r][k] * cw4[k*64 + uu];
        fused[r][uu] = fmaxf(s + cb4[uu], 0.f);
    }
    __syncthreads();
    if (t < 128) {
        int r = t >> 6, lane = t & 63;
        float v = fused[r][lane] * cw5[lane*2];
        #pragma unroll
        for (int off = 32; off; off >>= 1) v += __shfl_xor(v, off);
        if (lane == 0)
            gsh[r] = 1.f / (1.f + __expf(-(v + cb5[0] - thr[0])));
    }
    __syncthreads();
    #pragma unroll
    for (int idx = t; idx < 1024; idx += 256) {
        int r = idx >> 9, o = idx & 511;
        out0[(size_t)(b0 + r)*512 + o] = sp[r*512 + o] * gsh[r];
    }
}

extern "C" void kernel_launch(void* const* d_in, const int* in_sizes, int n_in,
                              void* d_out, int out_size, void* d_ws, size_t ws_size,
                              hipStream_t stream) {
    const float* x        = (const float*)d_in[0];
    const float* w_       = (const float*)d_in[1];
    const float* b_bias   = (const float*)d_in[2];
    const float* gate_w   = (const float*)d_in[3];
    const float* gate_b   = (const float*)d_in[4];
    const float* act_w    = (const float*)d_in[5];
    const float* mask     = (const float*)d_in[6];
    const float* mem      = (const float*)d_in[7];
    const float* att_w    = (const float*)d_in[8];
    const float* att_b    = (const float*)d_in[9];
    const float* write_w  = (const float*)d_in[10];
    const float* write_b  = (const float*)d_in[11];
    const float* upd_gate = (const float*)d_in[12];
    const float* out_w    = (const float*)d_in[13];
    const float* out_b    = (const float*)d_in[14];
    const float* cw1 = (const float*)d_in[15]; const float* cb1 = (const float*)d_in[16];
    const float* cw2 = (const float*)d_in[17]; const float* cb2 = (const float*)d_in[18];
    const float* cw3 = (const float*)d_in[19]; const float* cb3 = (const float*)d_in[20];
    const float* cw4 = (const float*)d_in[21]; const float* cb4 = (const float*)d_in[22];
    const float* cw5 = (const float*)d_in[23]; const float* cb5 = (const float*)d_in[24];
    const float* thr = (const float*)d_in[25];

    char* ws = (char*)d_ws;
    float* gate   = (float*)(ws + GATE_OFF);
    float* actw   = (float*)(ws + ACTW_OFF);
    float* uvec   = (float*)(ws + U_OFF);
    float* cmean  = (float*)(ws + CMEAN_OFF);
    float* part   = (float*)(ws + PART_OFF);
    bf16*  hidden = (bf16*)(ws + HIDDEN_OFF);
    bf16*  ratt   = (bf16*)(ws + RATT_OFF);
    bf16*  cand   = (bf16*)(ws + CAND_OFF);
    float* preds  = (float*)(ws + PREDS_OFF);
    float* readv  = (float*)(ws + READ_OFF);
    float* readv2 = (float*)(ws + READ2_OFF);   // aliases wT head (dead after G1): 3 partials
    bf16*  xbf    = (bf16*)(ws + XBF_OFF);
    bf16*  wT     = (bf16*)(ws + WT_OFF);
    bf16*  catT   = (bf16*)(ws + CATT_OFF);
    bf16*  memT   = (bf16*)(ws + MEMT_OFF);

    float* out0 = (float*)d_out;            // (1024, 512)
    float* out1 = out0 + 1024*512;          // (2048, 1024)

    // prepass: cvt+gate fused + wT transpose — 3072 blocks
    k_prepass<<<3072, 256, 0, stream>>>(x, xbf, gate_w, gate_b, act_w, gate, actw, w_, wT);

    // G1 fused: hidden = qact((x@w + b)·gate)*mask  [M=1024,N=8192,K=1024, TM=128, 512 blocks]
    // + 2304 trailing transpose blocks (att/write/out -> catT, mem -> memT)
    k_g1x<<<2816, 256, 0, stream>>>(xbf, wT, b_bias, hidden, gate, actw, mask,
                                    att_w, write_w, out_w, catT, mem, memT);

    // G234 fused: [att|write|out] heads            [M=1024, N=3584, K=2048] — 448 blocks
    gemm_bt<5, 64><<<dim3(28, 16), 256, 0, stream>>>(hidden, catT, 2048, 2048, 2048, 0,
        att_b, write_b, out_b, preds, nullptr, ratt, cand, nullptr, nullptr, nullptr, 0);
    k_softmax<<<1024, 256, 0, stream>>>(ratt);
    // G5 fused: read = ratt @ mem split-K=4 (512 blocks) + colpart (96 trailing)
    k_g5x<<<608, 256, 0, stream>>>(ratt, memT, cand, readv, readv2, part);

    k_colfin<<<12, 256, 0, stream>>>(part, upd_gate, uvec, cmean);
    // final: critic (512) + vectorized newmem (2048) in one dispatch
    k_fin<<<2560, 256, 0, stream>>>(readv, readv2, preds, hidden,
        cw1, cb1, cw2, cb2, cw3, cb3, cw4, cb4, cw5, cb5, thr, out0,
        mem, uvec, cmean, out1);
}

// Round 8
// 256.180 us; speedup vs baseline: 2.2746x; 1.0104x over previous
//
#include <hip/hip_runtime.h>
#include <hip/hip_bf16.h>
#include <math.h>

typedef __attribute__((ext_vector_type(4))) float f32x4;
typedef __attribute__((ext_vector_type(2))) float f32x2;
typedef __attribute__((ext_vector_type(8))) short s16x8;
typedef __attribute__((ext_vector_type(4))) short s16x4;
typedef __hip_bfloat16 bf16;

#define MB (1024ull*1024ull)
// workspace layout (bytes) — total 53 MB
#define GATE_OFF    (0ull)
#define ACTW_OFF    (16ull*1024)
#define U_OFF       (20ull*1024)
#define CMEAN_OFF   (28ull*1024)
#define PART_OFF    (64ull*1024)
#define HIDDEN_OFF  (1ull*MB)
#define RATT_OFF    (5ull*MB)
#define CAND_OFF    (9ull*MB)
#define PREDS_OFF   (11ull*MB)
#define READ_OFF    (13ull*MB)
#define XBF_OFF     (17ull*MB)
#define WT_OFF      (19ull*MB)      // bf16 8192x1024 (16MB); G5 partials alias head after G1
#define CATT_OFF    (35ull*MB)      // bf16 3584x2048 (14MB)
#define MEMT_OFF    (49ull*MB)      // bf16 1024x2048 (4MB)
#define READ2_OFF   WT_OFF

__device__ __forceinline__ short f2bf_s(float f) {
    bf16 h = __float2bfloat16(f);
    return *reinterpret_cast<short*>(&h);
}

__device__ __forceinline__ void async_load16(const bf16* g, short* l) {
    __builtin_amdgcn_global_load_lds((const __attribute__((address_space(1))) void*)g,
                                     (__attribute__((address_space(3))) void*)l, 16, 0, 0);
}

__device__ __forceinline__ float fast_tanh(float x) {
    float e2x = __expf(2.f * x);
    return 1.f - 2.f / (e2x + 1.f);
}

// fast 9-way activation mix — __expf algebra only (validated round 9)
__device__ __forceinline__ float qact(float x, const float* w) {
    float ex  = __expf(x);
    float r1  = 1.f / (1.f + ex);
    float sig = 1.f - r1;
    float em1 = ex - 1.f;
    float elu = x > 0.f ? x : em1;
    float e2x = ex * ex;
    float th  = 1.f - 2.f / (e2x + 1.f);
    float rel = fmaxf(x, 0.f);
    float silu = x * sig;
    float u   = 0.7978845608028654f * (x + 0.044715f * x * x * x);
    float e2u = __expf(2.f * u);
    float gel = x * (1.f - 1.f / (e2u + 1.f));
    float sel = 1.0507009873554805f * (x > 0.f ? x : 1.6732632423543772f * em1);
    float t   = 1.f + ex;
    float t2  = t * t;
    float mish = x * (1.f - 2.f / (t2 + 1.f));
    return w[0]*sig + w[1]*elu + w[2]*th + w[3]*rel + w[4]*silu
         + w[5]*gel + w[6]*sel + w[7]*mish + w[8]*x;
}

// ---------------- 64x64 f32 -> bf16 transpose tile (f32x2 loads; scratch 64x66 shorts) ----------------
__device__ __forceinline__ void do_transpose(const float* __restrict__ in,
                                             bf16* __restrict__ out, int R, int C,
                                             int bx, int by, int t, short* tile) {
    int k0 = by*64, n0 = bx*64;
    int i = t & 31, half = t >> 5;            // half = 0..7 over 256 threads
    #pragma unroll
    for (int r = 0; r < 8; r++) {
        int k = half + r*8;
        f32x2 v = *reinterpret_cast<const f32x2*>(&in[(size_t)(k0 + k)*C + n0 + i*2]);
        tile[(i*2 + 0)*66 + k] = f2bf_s(v[0]);
        tile[(i*2 + 1)*66 + k] = f2bf_s(v[1]);
    }
    __syncthreads();
    int kp = t & 31, nrow = t >> 5;
    #pragma unroll
    for (int jj = 0; jj < 8; jj++) {
        int n = nrow + jj*8;
        unsigned lo = (unsigned short)tile[n*66 + kp*2];
        unsigned hi = (unsigned short)tile[n*66 + kp*2 + 1];
        *reinterpret_cast<unsigned*>(&out[(size_t)(n0 + n)*R + k0 + kp*2]) = lo | (hi << 16);
    }
}

// ---------------- fused prepass: cvt+gate (fused, round 18) + wT transpose ----------------
// Round 18: gate dot-product fused into the cvt block — block b already holds x row b in
// registers. Block map: [0,1024) cvt+gate; [1024,3072) wT transpose.
__global__ __launch_bounds__(256) void k_prepass(
        const float* __restrict__ x, bf16* __restrict__ xbf,
        const float* __restrict__ gw, const float* __restrict__ gb,
        const float* __restrict__ aw_in,
        float* __restrict__ gate, float* __restrict__ actw,
        const float* __restrict__ w_, bf16* __restrict__ wT) {
    __shared__ short tile[64*66];
    int blk = blockIdx.x, t = threadIdx.x;
    if (blk < 1024) {
        int b = blk;                       // this block owns x row b
        f32x4 v = ((const f32x4*)x)[b*256 + t];
        s16x4 o;
        #pragma unroll
        for (int j = 0; j < 4; j++) o[j] = f2bf_s(v[j]);
        ((s16x4*)xbf)[b*256 + t] = o;
        // gate logits from the same registers: k = 4t+j
        const f32x4* gwv = (const f32x4*)gw;      // gw row i = all 4 branch weights for k=i
        f32x4 a = v[0] * gwv[4*t + 0];
        a += v[1] * gwv[4*t + 1];
        a += v[2] * gwv[4*t + 2];
        a += v[3] * gwv[4*t + 3];
        #pragma unroll
        for (int off = 32; off; off >>= 1) {
            #pragma unroll
            for (int j = 0; j < 4; j++) a[j] += __shfl_xor(a[j], off);
        }
        float* red = (float*)tile;
        int w = t >> 6, lane = t & 63;
        if (lane == 0) *reinterpret_cast<f32x4*>(&red[w*4]) = a;
        __syncthreads();
        if (t == 0) {
            f32x4 s = *reinterpret_cast<f32x4*>(&red[0]);
            s += *reinterpret_cast<f32x4*>(&red[4]);
            s += *reinterpret_cast<f32x4*>(&red[8]);
            s += *reinterpret_cast<f32x4*>(&red[12]);
            float l0 = s[0] + gb[0], l1 = s[1] + gb[1], l2 = s[2] + gb[2], l3 = s[3] + gb[3];
            float m = fmaxf(fmaxf(l0, l1), fmaxf(l2, l3));
            float e0 = __expf(l0-m), e1 = __expf(l1-m), e2 = __expf(l2-m), e3 = __expf(l3-m);
            float inv = 1.f / (e0+e1+e2+e3);
            gate[b*4+0] = e0*inv; gate[b*4+1] = e1*inv;
            gate[b*4+2] = e2*inv; gate[b*4+3] = e3*inv;
        }
        // act-weight softmax (once; touches no shared state)
        if (blk == 0 && t == 64) {
            float aa[9]; float m = -1e30f;
            for (int i2 = 0; i2 < 9; i2++) { aa[i2] = aw_in[i2]; m = fmaxf(m, aa[i2]); }
            float ss = 0.f;
            for (int i2 = 0; i2 < 9; i2++) { aa[i2] = __expf(aa[i2]-m); ss += aa[i2]; }
            float inv = 1.f / ss;
            for (int i2 = 0; i2 < 9; i2++) actw[i2] = aa[i2]*inv;
        }
    } else {
        int rel = blk - 1024;                       // w_: 1024x8192, gridX=128
        do_transpose(w_, wT, 1024, 8192, rel & 127, rel >> 7, t, tile);
    }
}

// ---------------- GEMM (BT): C = A(MxK) @ Bt(NxK)^T, TMx128 tile, BK=32 ----------------
// Round 15: LDS k-slot XOR swizzle (SQ_LDS_BANK_CONFLICT 2.36M -> 262K, verified).
// Round 16: triple-buffered K-loop, counted vmcnt (never 0 mid-loop), raw s_barrier.
template <int TM>
union SMemT {
    struct { short a[3][TM*32]; short b[3][128*32]; } tl;
    float z[TM*32];
    short tr[64*66];
};

template <int MODE, int TM>
__device__ __forceinline__ void gemm_core(
        int bx, int by, int bz, SMemT<TM>& sm,
        const bf16* __restrict__ A, const bf16* __restrict__ Bt,
        int K, int lda, int ldb, int kOffset,
        const float* __restrict__ bias, const float* __restrict__ bias2,
        const float* __restrict__ bias3,
        float* __restrict__ outF, float* __restrict__ outF2,
        bf16* __restrict__ outH, bf16* __restrict__ outH2,
        const float* __restrict__ gate, const float* __restrict__ actw,
        const float* __restrict__ mask, int outStride) {
    constexpr int MI = TM / 32;
    int t = threadIdx.x, lane = t & 63;
    int rowBase = by * TM, colBase = bx * 128;
    int lm = lane & 15, lq = lane >> 4;
    int w = t >> 6;
    int qm = (w >> 1) * (TM/2), qn = (w & 1) * 64;

    A  += (size_t)kOffset * bz;
    Bt += (size_t)kOffset * bz;

    f32x4 acc[MI][4];
    #pragma unroll
    for (int i = 0; i < MI; i++)
        #pragma unroll
        for (int j = 0; j < 4; j++) acc[i][j] = (f32x4){0.f, 0.f, 0.f, 0.f};

    // B staging: chunks c = w*128 + lane (+64); source k pre-swizzled: s' = s ^ ((row>>1)&3)
    int cb0 = w*128 + lane, cb1 = cb0 + 64;
    int rb0 = cb0 >> 2, kb0 = ((cb0 & 3) ^ ((rb0 >> 1) & 3)) * 8;
    int rb1 = cb1 >> 2, kb1 = ((cb1 & 3) ^ ((rb1 >> 1) & 3)) * 8;
    // A staging
    int ca0 = (TM == 128) ? (w*128 + lane) : (w*64 + lane);
    int ra0 = ca0 >> 2, ka0 = ((ca0 & 3) ^ ((ra0 >> 1) & 3)) * 8;
    int ca1 = ca0 + 64;
    int ra1 = ca1 >> 2, ka1 = ((ca1 & 3) ^ ((ra1 >> 1) & 3)) * 8;   // TM=128 only

    auto issueLoads = [&](int k0, int ib) {
        short* bA = sm.tl.a[ib];
        short* bB = sm.tl.b[ib];
        async_load16(A + (size_t)(rowBase + ra0)*lda + k0 + ka0,
                     bA + ((TM == 128) ? w*1024 : w*512));
        if (TM == 128)
            async_load16(A + (size_t)(rowBase + ra1)*lda + k0 + ka1, bA + w*1024 + 512);
        async_load16(Bt + (size_t)(colBase + rb0)*ldb + k0 + kb0, bB + w*1024);
        async_load16(Bt + (size_t)(colBase + rb1)*ldb + k0 + kb1, bB + w*1024 + 512);
    };

    issueLoads(0, 0);
    if (32 < K) issueLoads(32, 1);
    int ib = 0;
    for (int k0 = 0; k0 < K; k0 += 32) {
        // wait for THIS step's loads only; k+1/k+2 stay in flight across the barrier (T4)
        if (k0 + 32 < K) {
            if (TM == 128) asm volatile("s_waitcnt vmcnt(4)" ::: "memory");
            else           asm volatile("s_waitcnt vmcnt(3)" ::: "memory");
        } else {
            asm volatile("s_waitcnt vmcnt(0)" ::: "memory");
        }
        __builtin_amdgcn_sched_barrier(0);
        __builtin_amdgcn_s_barrier();
        __builtin_amdgcn_sched_barrier(0);
        int ibn = ib + 2; if (ibn >= 3) ibn -= 3;
        if (k0 + 64 < K) issueLoads(k0 + 64, ibn);
        const short* cA = sm.tl.a[ib];
        const short* cB = sm.tl.b[ib];
        s16x8 af[MI], bfr[4];
        #pragma unroll
        for (int mi = 0; mi < MI; mi++) {
            int r = qm + mi*16 + lm;
            af[mi] = *reinterpret_cast<const s16x8*>(cA + r*32 + ((lq ^ ((r >> 1) & 3)) * 8));
        }
        #pragma unroll
        for (int ni = 0; ni < 4; ni++) {
            int r = qn + ni*16 + lm;
            bfr[ni] = *reinterpret_cast<const s16x8*>(cB + r*32 + ((lq ^ ((r >> 1) & 3)) * 8));
        }
        #pragma unroll
        for (int mi = 0; mi < MI; mi++)
            #pragma unroll
            for (int ni = 0; ni < 4; ni++)
                acc[mi][ni] = __builtin_amdgcn_mfma_f32_16x16x32_bf16(af[mi], bfr[ni], acc[mi][ni], 0, 0, 0);
        ib += 1; if (ib >= 3) ib = 0;
    }

    if (MODE == 4) {
        __syncthreads();   // all tile reads done; safe to overlay sm.z
        #pragma unroll
        for (int mi = 0; mi < MI; mi++) {
            int rowl0 = qm + mi*16 + lq*4;
            #pragma unroll
            for (int ni = 0; ni < 4; ni++) {
                int col = colBase + qn + ni*16 + lm;
                int n = col & 3;
                float bb = bias[col];
                f32x4 v = acc[mi][ni];
                #pragma unroll
                for (int r = 0; r < 4; r++) v[r] = (v[r] + bb) * gate[(rowBase + rowl0 + r)*4 + n];
                #pragma unroll
                for (int r = 0; r < 4; r++) v[r] += __shfl_xor(v[r], 1);
                #pragma unroll
                for (int r = 0; r < 4; r++) v[r] += __shfl_xor(v[r], 2);
                if ((lane & 3) == 0) {
                    int ul = ((w & 1) << 4) + ni*4 + (lm >> 2);
                    #pragma unroll
                    for (int r = 0; r < 4; r++)
                        sm.z[(rowl0 + r)*32 + ul] = v[r];
                }
            }
        }
        __syncthreads();
        float aw[9];
        #pragma unroll
        for (int i = 0; i < 9; i++) aw[i] = actw[i];
        int u0 = colBase >> 2;
        #pragma unroll
        for (int i = 0; i < TM/8; i++) {
            int idx = t + i*256;
            int row = idx >> 5, ul = idx & 31;
            int ug = u0 + ul;
            float zz = sm.z[idx];
            outH[(size_t)(rowBase + row)*outStride + ug] = __float2bfloat16(qact(zz, aw) * mask[ug]);
        }
    } else if (MODE == 5) {
        #pragma unroll
        for (int mi = 0; mi < MI; mi++) {
            int row0 = rowBase + qm + mi*16 + lq*4;
            #pragma unroll
            for (int ni = 0; ni < 4; ni++) {
                int col = colBase + qn + ni*16 + lm;
                if (col < 2048) {
                    float bb = bias[col];
                    #pragma unroll
                    for (int r = 0; r < 4; r++)
                        outH[(size_t)(row0 + r)*2048 + col] = __float2bfloat16(acc[mi][ni][r] + bb);
                } else if (col < 3072) {
                    int c = col - 2048;
                    float bb = bias2[c];
                    #pragma unroll
                    for (int r = 0; r < 4; r++)
                        outH2[(size_t)(row0 + r)*1024 + c] = __float2bfloat16(fast_tanh(acc[mi][ni][r] + bb));
                } else {
                    int c = col - 3072;
                    float bb = bias3[c];
                    #pragma unroll
                    for (int r = 0; r < 4; r++)
                        outF[(size_t)(row0 + r)*512 + c] = acc[mi][ni][r] + bb;
                }
            }
        }
    } else {  // MODE 3 (split-K partial, z in [0,4): partial 0 -> outF, z>0 -> outF2 + (z-1)*1M floats)
        float* of = bz ? (outF2 + (size_t)(bz - 1) * 1048576) : outF;
        #pragma unroll
        for (int mi = 0; mi < MI; mi++) {
            int row0 = rowBase + qm + mi*16 + lq*4;
            #pragma unroll
            for (int ni = 0; ni < 4; ni++) {
                int col = colBase + qn + ni*16 + lm;
                #pragma unroll
                for (int r = 0; r < 4; r++)
                    of[(size_t)(row0 + r)*outStride + col] = acc[mi][ni][r];
            }
        }
    }
}

template <int MODE, int TM>
__global__ __launch_bounds__(256, 2) void gemm_bt(
        const bf16* __restrict__ A, const bf16* __restrict__ Bt,
        int K, int lda, int ldb, int kOffset,
        const float* __restrict__ bias, const float* __restrict__ bias2,
        const float* __restrict__ bias3,
        float* __restrict__ outF, float* __restrict__ outF2,
        bf16* __restrict__ outH, bf16* __restrict__ outH2,
        const float* __restrict__ gate, const float* __restrict__ actw,
        const float* __restrict__ mask, int outStride) {
    __shared__ __align__(16) SMemT<TM> sm;
    gemm_core<MODE, TM>(blockIdx.x, blockIdx.y, blockIdx.z, sm,
                        A, Bt, K, lda, ldb, kOffset, bias, bias2, bias3,
                        outF, outF2, outH, outH2, gate, actw, mask, outStride);
}

// ---------------- G1 fused dispatch: capacity-matched interleave (round 19) ----------------
// LDS 48KB -> 3 blocks/CU = 768 resident. First 768 blocks = 256 groups of {2 gemm, 1
// transpose}: full 512-block gemm grid at 2/CU from t=0 (same residency as round 7) PLUS
// 1 transpose block/CU eating the idle memory pipe during the gemm phase. Remaining 2048
// transposes trail. (Round-2's 2:9 interleave starved gemm to 2/11 of first wave — the
// ratio, not the idea, was wrong.)
__global__ __launch_bounds__(256, 2) void k_g1x(
        const bf16* __restrict__ xbf, const bf16* __restrict__ wT,
        const float* __restrict__ bias, bf16* __restrict__ hidden,
        const float* __restrict__ gate, const float* __restrict__ actw,
        const float* __restrict__ mask,
        const float* __restrict__ att_w, const float* __restrict__ write_w,
        const float* __restrict__ out_w, bf16* __restrict__ catT,
        const float* __restrict__ mem, bf16* __restrict__ memT) {
    __shared__ __align__(16) SMemT<128> sm;
    int bid = blockIdx.x, t = threadIdx.x;
    int gemmId = -1, trId;
    if (bid < 768) {
        int g = bid / 3, r = bid - g*3;
        if (r < 2) gemmId = g*2 + r;               // 0..511
        else       trId = g;                       // 0..255
    } else {
        trId = 256 + (bid - 768);                  // 256..2303
    }
    if (gemmId >= 0) {
        gemm_core<4, 128>(gemmId & 63, gemmId >> 6, 0, sm, xbf, wT, 1024, 1024, 1024, 0,
                          bias, nullptr, nullptr, nullptr, nullptr, hidden, nullptr,
                          gate, actw, mask, 2048);
    } else {
        int rel = trId;
        if (rel < 1024) {
            do_transpose(att_w, catT, 2048, 2048, rel & 31, rel >> 5, t, sm.tr);
        } else if (rel < 1536) {
            rel -= 1024;
            do_transpose(write_w, catT + 2048ull*2048, 2048, 1024, rel & 15, rel >> 4, t, sm.tr);
        } else if (rel < 1792) {
            rel -= 1536;
            do_transpose(out_w, catT + 3072ull*2048, 2048, 512, rel & 7, rel >> 3, t, sm.tr);
        } else {
            rel -= 1792;
            do_transpose(mem, memT, 2048, 1024, rel & 15, rel >> 4, t, sm.tr);
        }
    }
}

// ---------------- in-place row softmax over 2048 cols (bf16 buffer) ----------------
__global__ __launch_bounds__(256) void k_softmax(bf16* __restrict__ ratt) {
    int b = blockIdx.x, t = threadIdx.x, w = t >> 6, lane = t & 63;
    __shared__ float red[8];
    bf16* row = ratt + (size_t)b*2048;
    float v[8];
    float mx = -1e30f;
    #pragma unroll
    for (int j = 0; j < 8; j++) {
        v[j] = __bfloat162float(row[t + j*256]);
        mx = fmaxf(mx, v[j]);
    }
    #pragma unroll
    for (int off = 32; off; off >>= 1) mx = fmaxf(mx, __shfl_xor(mx, off));
    if (lane == 0) red[w] = mx;
    __syncthreads();
    mx = fmaxf(fmaxf(red[0], red[1]), fmaxf(red[2], red[3]));
    float s = 0.f;
    #pragma unroll
    for (int j = 0; j < 8; j++) { v[j] = __expf(v[j] - mx); s += v[j]; }
    #pragma unroll
    for (int off = 32; off; off >>= 1) s += __shfl_xor(s, off);
    if (lane == 0) red[4 + w] = s;
    __syncthreads();
    float inv = 1.f / (red[4] + red[5] + red[6] + red[7]);
    #pragma unroll
    for (int j = 0; j < 8; j++)
        row[t + j*256] = __float2bfloat16(v[j] * inv);
}

// ---------------- G5 fused dispatch: split-K read GEMM (512 blocks) + colpart (96 trailing) ----------------
__global__ __launch_bounds__(256, 2) void k_g5x(
        const bf16* __restrict__ ratt, const bf16* __restrict__ memT,
        const bf16* __restrict__ cand,
        float* __restrict__ readv, float* __restrict__ readv2,
        float* __restrict__ part) {
    __shared__ __align__(16) SMemT<64> sm;
    int bid = blockIdx.x, t = threadIdx.x;
    if (bid < 512) {
        int bx = bid & 7, by = (bid >> 3) & 15, bz = bid >> 7;
        gemm_core<3, 64>(bx, by, bz, sm, ratt, memT, 512, 2048, 2048, 512,
                         nullptr, nullptr, nullptr, readv, readv2, nullptr, nullptr,
                         nullptr, nullptr, nullptr, 1024);
    } else {
        int rel = bid - 512;                       // 96 colpart blocks: 12 x 8
        int ct = rel % 12, rc = rel / 12;
        int col = ct*256 + t;
        const bf16* src; int stride, c;
        if (ct < 8) { src = ratt; stride = 2048; c = col; }
        else        { src = cand; stride = 1024; c = col - 2048; }
        float s = 0.f;
        int r0 = rc*128;
        for (int r2 = 0; r2 < 128; r2++)
            s += __bfloat162float(src[(size_t)(r0 + r2)*stride + c]);
        part[rc*3072 + col] = s;
    }
}

__global__ __launch_bounds__(256) void k_colfin(const float* __restrict__ part,
                                                const float* __restrict__ update_gate,
                                                float* __restrict__ u,
                                                float* __restrict__ cmean) {
    int col = blockIdx.x*256 + threadIdx.x;
    float s = 0.f;
    #pragma unroll
    for (int rc = 0; rc < 8; rc++) s += part[rc*3072 + col];
    s *= (1.f/1024.f);
    if (col < 2048) u[col] = s * update_gate[col];
    else            cmean[col - 2048] = s;
}

// ---------------- final fused dispatch: critic (512 blocks) + vectorized newmem (2048 blocks) ----------------
// critic: 2 rows/block, f32x4 weight loads (round-10 validated); sums 4 split-K read partials.
__global__ __launch_bounds__(256) void k_fin(
        const float* __restrict__ readv, const float* __restrict__ readv2,
        const float* __restrict__ preds, const bf16* __restrict__ hidden,
        const float* cw1, const float* cb1, const float* cw2, const float* cb2,
        const float* cw3, const float* cb3, const float* cw4, const float* cb4,
        const float* cw5, const float* cb5, const float* thr,
        float* __restrict__ out0,
        const float* __restrict__ mem, const float* __restrict__ u,
        const float* __restrict__ cmean, float* __restrict__ out1) {
    __shared__ __align__(16) float sx[2*1024];
    __shared__ __align__(16) float sp[2*512];
    __shared__ __align__(16) short sh[2*2048];
    __shared__ __align__(16) f32x4 part[2][32][8];
    __shared__ float feat[2][96];
    __shared__ float fused[2][64];
    __shared__ float gsh[2];
    int bid = blockIdx.x, t = threadIdx.x;
    if (bid >= 512) {
        // new_mem blend, f32x4-vectorized: idx over 2048x1024 f32 in groups of 4
        int idx = (bid - 512)*256 + t;             // f32x4 index, 524288 total
        int m = idx >> 8, d4 = idx & 255;
        float um = u[m];
        f32x4 m4 = ((const f32x4*)mem)[idx];
        f32x4 c4 = ((const f32x4*)cmean)[d4];
        f32x4 o;
        #pragma unroll
        for (int j = 0; j < 4; j++) o[j] = m4[j] * (1.f - um) + um * c4[j];
        ((f32x4*)out1)[idx] = o;
        return;
    }
    int b0 = bid * 2;
    int j4 = t & 7, kg = t >> 3;

    {
        const f32x4* r0 = (const f32x4*)(readv  + (size_t)b0*1024);
        const f32x4* r1 = (const f32x4*)(readv2 + (size_t)b0*1024);
        const f32x4* r2 = (const f32x4*)(readv2 + 1048576 + (size_t)b0*1024);
        const f32x4* r3 = (const f32x4*)(readv2 + 2097152 + (size_t)b0*1024);
        ((f32x4*)sx)[t]       = r0[t] + r1[t] + r2[t] + r3[t];
        ((f32x4*)sx)[t + 256] = r0[t + 256] + r1[t + 256] + r2[t + 256] + r3[t + 256];
    }
    ((f32x4*)sp)[t]       = ((const f32x4*)(preds + (size_t)b0*512))[t];
    ((s16x8*)sh)[t]       = ((const s16x8*)(hidden + (size_t)b0*2048))[t];
    ((s16x8*)sh)[t + 256] = ((const s16x8*)(hidden + (size_t)b0*2048))[t + 256];
    __syncthreads();

    {
        const f32x4* wv = (const f32x4*)cw1;
        f32x4 a0 = (f32x4){0,0,0,0}, a1 = (f32x4){0,0,0,0};
        int k0 = kg*32;
        #pragma unroll 4
        for (int k = k0; k < k0 + 32; k++) {
            f32x4 wq = wv[k*8 + j4];
            a0 += sx[k] * wq;
            a1 += sx[1024 + k] * wq;
        }
        part[0][kg][j4] = a0; part[1][kg][j4] = a1;
    }
    __syncthreads();
    if (t < 64) {
        int r = t >> 5, f = t & 31;
        float s = 0.f;
        #pragma unroll
        for (int i = 0; i < 32; i++) s += part[r][i][f >> 2][f & 3];
        feat[r][f] = fmaxf(s + cb1[f], 0.f);
    }
    __syncthreads();
    {
        const f32x4* wv = (const f32x4*)cw2;
        f32x4 a0 = (f32x4){0,0,0,0}, a1 = (f32x4){0,0,0,0};
        int k0 = kg*16;
        #pragma unroll 4
        for (int k = k0; k < k0 + 16; k++) {
            f32x4 wq = wv[k*8 + j4];
            a0 += sp[k] * wq;
            a1 += sp[512 + k] * wq;
        }
        part[0][kg][j4] = a0; part[1][kg][j4] = a1;
    }
    __syncthreads();
    if (t < 64) {
        int r = t >> 5, f = t & 31;
        float s = 0.f;
        #pragma unroll
        for (int i = 0; i < 32; i++) s += part[r][i][f >> 2][f & 3];
        feat[r][32 + f] = fmaxf(s + cb2[f], 0.f);
    }
    __syncthreads();
    {
        const f32x4* wv = (const f32x4*)cw3;
        f32x4 a0 = (f32x4){0,0,0,0}, a1 = (f32x4){0,0,0,0};
        int k0 = kg*64;
        #pragma unroll 4
        for (int k = k0; k < k0 + 64; k++) {
            f32x4 wq = wv[k*8 + j4];
            float h0 = __bfloat162float(*reinterpret_cast<const bf16*>(&sh[k]));
            float h1 = __bfloat162float(*reinterpret_cast<const bf16*>(&sh[2048 + k]));
            a0 += h0 * wq;
            a1 += h1 * wq;
        }
        part[0][kg][j4] = a0; part[1][kg][j4] = a1;
    }
    __syncthreads();
    if (t < 64) {
        int r = t >> 5, f = t & 31;
        float s = 0.f;
        #pragma unroll
        for (int i = 0; i < 32; i++) s += part[r][i][f >> 2][f & 3];
        feat[r][64 + f] = fmaxf(s + cb3[f], 0.f);
    }
    __syncthreads();
    if (t < 128) {
        int r = t >> 6, uu = t & 63;
        float s = 0.f;
        #pragma unroll 8
        for (int k = 0; k < 96; k++) s += feat[r][k] * cw4[k*64 + uu];
        fused[r][uu] = fmaxf(s + cb4[uu], 0.f);
    }
    __syncthreads();
    if (t < 128) {
        int r = t >> 6, lane = t & 63;
        float v = fused[r][lane] * cw5[lane*2];
        #pragma unroll
        for (int off = 32; off; off >>= 1) v += __shfl_xor(v, off);
        if (lane == 0)
            gsh[r] = 1.f / (1.f + __expf(-(v + cb5[0] - thr[0])));
    }
    __syncthreads();
    #pragma unroll
    for (int idx = t; idx < 1024; idx += 256) {
        int r = idx >> 9, o = idx & 511;
        out0[(size_t)(b0 + r)*512 + o] = sp[r*512 + o] * gsh[r];
    }
}

extern "C" void kernel_launch(void* const* d_in, const int* in_sizes, int n_in,
                              void* d_out, int out_size, void* d_ws, size_t ws_size,
                              hipStream_t stream) {
    const float* x        = (const float*)d_in[0];
    const float* w_       = (const float*)d_in[1];
    const float* b_bias   = (const float*)d_in[2];
    const float* gate_w   = (const float*)d_in[3];
    const float* gate_b   = (const float*)d_in[4];
    const float* act_w    = (const float*)d_in[5];
    const float* mask     = (const float*)d_in[6];
    const float* mem      = (const float*)d_in[7];
    const float* att_w    = (const float*)d_in[8];
    const float* att_b    = (const float*)d_in[9];
    const float* write_w  = (const float*)d_in[10];
    const float* write_b  = (const float*)d_in[11];
    const float* upd_gate = (const float*)d_in[12];
    const float* out_w    = (const float*)d_in[13];
    const float* out_b    = (const float*)d_in[14];
    const float* cw1 = (const float*)d_in[15]; const float* cb1 = (const float*)d_in[16];
    const float* cw2 = (const float*)d_in[17]; const float* cb2 = (const float*)d_in[18];
    const float* cw3 = (const float*)d_in[19]; const float* cb3 = (const float*)d_in[20];
    const float* cw4 = (const float*)d_in[21]; const float* cb4 = (const float*)d_in[22];
    const float* cw5 = (const float*)d_in[23]; const float* cb5 = (const float*)d_in[24];
    const float* thr = (const float*)d_in[25];

    char* ws = (char*)d_ws;
    float* gate   = (float*)(ws + GATE_OFF);
    float* actw   = (float*)(ws + ACTW_OFF);
    float* uvec   = (float*)(ws + U_OFF);
    float* cmean  = (float*)(ws + CMEAN_OFF);
    float* part   = (float*)(ws + PART_OFF);
    bf16*  hidden = (bf16*)(ws + HIDDEN_OFF);
    bf16*  ratt   = (bf16*)(ws + RATT_OFF);
    bf16*  cand   = (bf16*)(ws + CAND_OFF);
    float* preds  = (float*)(ws + PREDS_OFF);
    float* readv  = (float*)(ws + READ_OFF);
    float* readv2 = (float*)(ws + READ2_OFF);   // aliases wT head (dead after G1): 3 partials
    bf16*  xbf    = (bf16*)(ws + XBF_OFF);
    bf16*  wT     = (bf16*)(ws + WT_OFF);
    bf16*  catT   = (bf16*)(ws + CATT_OFF);
    bf16*  memT   = (bf16*)(ws + MEMT_OFF);

    float* out0 = (float*)d_out;            // (1024, 512)
    float* out1 = out0 + 1024*512;          // (2048, 1024)

    // prepass: cvt+gate fused + wT transpose — 3072 blocks
    k_prepass<<<3072, 256, 0, stream>>>(x, xbf, gate_w, gate_b, act_w, gate, actw, w_, wT);

    // G1 fused: hidden = qact((x@w + b)·gate)*mask  [M=1024,N=8192,K=1024, TM=128, 512 blocks]
    // + 2304 transpose blocks, capacity-matched interleave (first 768 = 2 gemm : 1 transpose)
    k_g1x<<<2816, 256, 0, stream>>>(xbf, wT, b_bias, hidden, gate, actw, mask,
                                    att_w, write_w, out_w, catT, mem, memT);

    // G234 fused: [att|write|out] heads            [M=1024, N=3584, K=2048] — 448 blocks
    gemm_bt<5, 64><<<dim3(28, 16), 256, 0, stream>>>(hidden, catT, 2048, 2048, 2048, 0,
        att_b, write_b, out_b, preds, nullptr, ratt, cand, nullptr, nullptr, nullptr, 0);
    k_softmax<<<1024, 256, 0, stream>>>(ratt);
    // G5 fused: read = ratt @ mem split-K=4 (512 blocks) + colpart (96 trailing)
    k_g5x<<<608, 256, 0, stream>>>(ratt, memT, cand, readv, readv2, part);

    k_colfin<<<12, 256, 0, stream>>>(part, upd_gate, uvec, cmean);
    // final: critic (512) + vectorized newmem (2048) in one dispatch
    k_fin<<<2560, 256, 0, stream>>>(readv, readv2, preds, hidden,
        cw1, cb1, cw2, cb2, cw3, cb3, cw4, cb4, cw5, cb5, thr, out0,
        mem, uvec, cmean, out1);
}

// Round 9
// 255.579 us; speedup vs baseline: 2.2799x; 1.0024x over previous
//
#include <hip/hip_runtime.h>
#include <hip/hip_bf16.h>
#include <math.h>

typedef __attribute__((ext_vector_type(4))) float f32x4;
typedef __attribute__((ext_vector_type(2))) float f32x2;
typedef __attribute__((ext_vector_type(8))) short s16x8;
typedef __attribute__((ext_vector_type(4))) short s16x4;
typedef __hip_bfloat16 bf16;

#define MB (1024ull*1024ull)
// workspace layout (bytes) — total 53 MB
#define GATE_OFF    (0ull)
#define ACTW_OFF    (16ull*1024)
#define U_OFF       (20ull*1024)
#define CMEAN_OFF   (28ull*1024)
#define PART_OFF    (64ull*1024)
#define HIDDEN_OFF  (1ull*MB)
#define RATT_OFF    (5ull*MB)
#define CAND_OFF    (9ull*MB)
#define PREDS_OFF   (11ull*MB)
#define READ_OFF    (13ull*MB)
#define XBF_OFF     (17ull*MB)
#define WT_OFF      (19ull*MB)      // bf16 8192x1024 (16MB); G5 partials alias head after G1
#define CATT_OFF    (35ull*MB)      // bf16 3584x2048 (14MB)
#define MEMT_OFF    (49ull*MB)      // bf16 1024x2048 (4MB)
#define READ2_OFF   WT_OFF

__device__ __forceinline__ short f2bf_s(float f) {
    bf16 h = __float2bfloat16(f);
    return *reinterpret_cast<short*>(&h);
}

__device__ __forceinline__ void async_load16(const bf16* g, short* l) {
    __builtin_amdgcn_global_load_lds((const __attribute__((address_space(1))) void*)g,
                                     (__attribute__((address_space(3))) void*)l, 16, 0, 0);
}

__device__ __forceinline__ float fast_tanh(float x) {
    float e2x = __expf(2.f * x);
    return 1.f - 2.f / (e2x + 1.f);
}

// fast 9-way activation mix — __expf algebra only (validated round 9)
__device__ __forceinline__ float qact(float x, const float* w) {
    float ex  = __expf(x);
    float r1  = 1.f / (1.f + ex);
    float sig = 1.f - r1;
    float em1 = ex - 1.f;
    float elu = x > 0.f ? x : em1;
    float e2x = ex * ex;
    float th  = 1.f - 2.f / (e2x + 1.f);
    float rel = fmaxf(x, 0.f);
    float silu = x * sig;
    float u   = 0.7978845608028654f * (x + 0.044715f * x * x * x);
    float e2u = __expf(2.f * u);
    float gel = x * (1.f - 1.f / (e2u + 1.f));
    float sel = 1.0507009873554805f * (x > 0.f ? x : 1.6732632423543772f * em1);
    float t   = 1.f + ex;
    float t2  = t * t;
    float mish = x * (1.f - 2.f / (t2 + 1.f));
    return w[0]*sig + w[1]*elu + w[2]*th + w[3]*rel + w[4]*silu
         + w[5]*gel + w[6]*sel + w[7]*mish + w[8]*x;
}

// ---------------- 64x64 f32 -> bf16 transpose tile (round 20: f32x4 loads) ----------------
// Each lane loads 4 consecutive n (16B); 16 lanes/k-row, 16 k-rows/pass, 4 passes.
__device__ __forceinline__ void do_transpose(const float* __restrict__ in,
                                             bf16* __restrict__ out, int R, int C,
                                             int bx, int by, int t, short* tile) {
    int k0 = by*64, n0 = bx*64;
    int i = t & 15, kr = t >> 4;              // i = n-group, kr = 0..15
    #pragma unroll
    for (int r = 0; r < 4; r++) {
        int k = kr + r*16;
        f32x4 v = *reinterpret_cast<const f32x4*>(&in[(size_t)(k0 + k)*C + n0 + i*4]);
        #pragma unroll
        for (int j = 0; j < 4; j++)
            tile[(i*4 + j)*66 + k] = f2bf_s(v[j]);
    }
    __syncthreads();
    int kp = t & 31, nrow = t >> 5;
    #pragma unroll
    for (int jj = 0; jj < 8; jj++) {
        int n = nrow + jj*8;
        unsigned lo = (unsigned short)tile[n*66 + kp*2];
        unsigned hi = (unsigned short)tile[n*66 + kp*2 + 1];
        *reinterpret_cast<unsigned*>(&out[(size_t)(n0 + n)*R + k0 + kp*2]) = lo | (hi << 16);
    }
}

// ---------------- fused prepass: cvt+gate (fused, round 18) + wT transpose ----------------
__global__ __launch_bounds__(256) void k_prepass(
        const float* __restrict__ x, bf16* __restrict__ xbf,
        const float* __restrict__ gw, const float* __restrict__ gb,
        const float* __restrict__ aw_in,
        float* __restrict__ gate, float* __restrict__ actw,
        const float* __restrict__ w_, bf16* __restrict__ wT) {
    __shared__ short tile[64*66];
    int blk = blockIdx.x, t = threadIdx.x;
    if (blk < 1024) {
        int b = blk;                       // this block owns x row b
        f32x4 v = ((const f32x4*)x)[b*256 + t];
        s16x4 o;
        #pragma unroll
        for (int j = 0; j < 4; j++) o[j] = f2bf_s(v[j]);
        ((s16x4*)xbf)[b*256 + t] = o;
        // gate logits from the same registers: k = 4t+j
        const f32x4* gwv = (const f32x4*)gw;      // gw row i = all 4 branch weights for k=i
        f32x4 a = v[0] * gwv[4*t + 0];
        a += v[1] * gwv[4*t + 1];
        a += v[2] * gwv[4*t + 2];
        a += v[3] * gwv[4*t + 3];
        #pragma unroll
        for (int off = 32; off; off >>= 1) {
            #pragma unroll
            for (int j = 0; j < 4; j++) a[j] += __shfl_xor(a[j], off);
        }
        float* red = (float*)tile;
        int w = t >> 6, lane = t & 63;
        if (lane == 0) *reinterpret_cast<f32x4*>(&red[w*4]) = a;
        __syncthreads();
        if (t == 0) {
            f32x4 s = *reinterpret_cast<f32x4*>(&red[0]);
            s += *reinterpret_cast<f32x4*>(&red[4]);
            s += *reinterpret_cast<f32x4*>(&red[8]);
            s += *reinterpret_cast<f32x4*>(&red[12]);
            float l0 = s[0] + gb[0], l1 = s[1] + gb[1], l2 = s[2] + gb[2], l3 = s[3] + gb[3];
            float m = fmaxf(fmaxf(l0, l1), fmaxf(l2, l3));
            float e0 = __expf(l0-m), e1 = __expf(l1-m), e2 = __expf(l2-m), e3 = __expf(l3-m);
            float inv = 1.f / (e0+e1+e2+e3);
            gate[b*4+0] = e0*inv; gate[b*4+1] = e1*inv;
            gate[b*4+2] = e2*inv; gate[b*4+3] = e3*inv;
        }
        // act-weight softmax (once; touches no shared state)
        if (blk == 0 && t == 64) {
            float aa[9]; float m = -1e30f;
            for (int i2 = 0; i2 < 9; i2++) { aa[i2] = aw_in[i2]; m = fmaxf(m, aa[i2]); }
            float ss = 0.f;
            for (int i2 = 0; i2 < 9; i2++) { aa[i2] = __expf(aa[i2]-m); ss += aa[i2]; }
            float inv = 1.f / ss;
            for (int i2 = 0; i2 < 9; i2++) actw[i2] = aa[i2]*inv;
        }
    } else {
        int rel = blk - 1024;                       // w_: 1024x8192, gridX=128
        do_transpose(w_, wT, 1024, 8192, rel & 127, rel >> 7, t, tile);
    }
}

// ---------------- GEMM (BT): C = A(MxK) @ Bt(NxK)^T, TMx128 tile, BK=32 ----------------
// Round 15: LDS k-slot XOR swizzle (SQ_LDS_BANK_CONFLICT 2.36M -> 262K, verified).
// Round 16: triple-buffered K-loop, counted vmcnt (never 0 mid-loop), raw s_barrier.
template <int TM>
union SMemT {
    struct { short a[3][TM*32]; short b[3][128*32]; } tl;
    float z[TM*32];
    short tr[64*66];
};

template <int MODE, int TM>
__device__ __forceinline__ void gemm_core(
        int bx, int by, int bz, SMemT<TM>& sm,
        const bf16* __restrict__ A, const bf16* __restrict__ Bt,
        int K, int lda, int ldb, int kOffset,
        const float* __restrict__ bias, const float* __restrict__ bias2,
        const float* __restrict__ bias3,
        float* __restrict__ outF, float* __restrict__ outF2,
        bf16* __restrict__ outH, bf16* __restrict__ outH2,
        const float* __restrict__ gate, const float* __restrict__ actw,
        const float* __restrict__ mask, int outStride) {
    constexpr int MI = TM / 32;
    int t = threadIdx.x, lane = t & 63;
    int rowBase = by * TM, colBase = bx * 128;
    int lm = lane & 15, lq = lane >> 4;
    int w = t >> 6;
    int qm = (w >> 1) * (TM/2), qn = (w & 1) * 64;

    A  += (size_t)kOffset * bz;
    Bt += (size_t)kOffset * bz;

    f32x4 acc[MI][4];
    #pragma unroll
    for (int i = 0; i < MI; i++)
        #pragma unroll
        for (int j = 0; j < 4; j++) acc[i][j] = (f32x4){0.f, 0.f, 0.f, 0.f};

    // B staging: chunks c = w*128 + lane (+64); source k pre-swizzled: s' = s ^ ((row>>1)&3)
    int cb0 = w*128 + lane, cb1 = cb0 + 64;
    int rb0 = cb0 >> 2, kb0 = ((cb0 & 3) ^ ((rb0 >> 1) & 3)) * 8;
    int rb1 = cb1 >> 2, kb1 = ((cb1 & 3) ^ ((rb1 >> 1) & 3)) * 8;
    // A staging
    int ca0 = (TM == 128) ? (w*128 + lane) : (w*64 + lane);
    int ra0 = ca0 >> 2, ka0 = ((ca0 & 3) ^ ((ra0 >> 1) & 3)) * 8;
    int ca1 = ca0 + 64;
    int ra1 = ca1 >> 2, ka1 = ((ca1 & 3) ^ ((ra1 >> 1) & 3)) * 8;   // TM=128 only

    auto issueLoads = [&](int k0, int ib) {
        short* bA = sm.tl.a[ib];
        short* bB = sm.tl.b[ib];
        async_load16(A + (size_t)(rowBase + ra0)*lda + k0 + ka0,
                     bA + ((TM == 128) ? w*1024 : w*512));
        if (TM == 128)
            async_load16(A + (size_t)(rowBase + ra1)*lda + k0 + ka1, bA + w*1024 + 512);
        async_load16(Bt + (size_t)(colBase + rb0)*ldb + k0 + kb0, bB + w*1024);
        async_load16(Bt + (size_t)(colBase + rb1)*ldb + k0 + kb1, bB + w*1024 + 512);
    };

    issueLoads(0, 0);
    if (32 < K) issueLoads(32, 1);
    int ib = 0;
    for (int k0 = 0; k0 < K; k0 += 32) {
        // wait for THIS step's loads only; k+1/k+2 stay in flight across the barrier (T4)
        if (k0 + 32 < K) {
            if (TM == 128) asm volatile("s_waitcnt vmcnt(4)" ::: "memory");
            else           asm volatile("s_waitcnt vmcnt(3)" ::: "memory");
        } else {
            asm volatile("s_waitcnt vmcnt(0)" ::: "memory");
        }
        __builtin_amdgcn_sched_barrier(0);
        __builtin_amdgcn_s_barrier();
        __builtin_amdgcn_sched_barrier(0);
        int ibn = ib + 2; if (ibn >= 3) ibn -= 3;
        if (k0 + 64 < K) issueLoads(k0 + 64, ibn);
        const short* cA = sm.tl.a[ib];
        const short* cB = sm.tl.b[ib];
        s16x8 af[MI], bfr[4];
        #pragma unroll
        for (int mi = 0; mi < MI; mi++) {
            int r = qm + mi*16 + lm;
            af[mi] = *reinterpret_cast<const s16x8*>(cA + r*32 + ((lq ^ ((r >> 1) & 3)) * 8));
        }
        #pragma unroll
        for (int ni = 0; ni < 4; ni++) {
            int r = qn + ni*16 + lm;
            bfr[ni] = *reinterpret_cast<const s16x8*>(cB + r*32 + ((lq ^ ((r >> 1) & 3)) * 8));
        }
        #pragma unroll
        for (int mi = 0; mi < MI; mi++)
            #pragma unroll
            for (int ni = 0; ni < 4; ni++)
                acc[mi][ni] = __builtin_amdgcn_mfma_f32_16x16x32_bf16(af[mi], bfr[ni], acc[mi][ni], 0, 0, 0);
        ib += 1; if (ib >= 3) ib = 0;
    }

    if (MODE == 4) {
        __syncthreads();   // all tile reads done; safe to overlay sm.z
        #pragma unroll
        for (int mi = 0; mi < MI; mi++) {
            int rowl0 = qm + mi*16 + lq*4;
            #pragma unroll
            for (int ni = 0; ni < 4; ni++) {
                int col = colBase + qn + ni*16 + lm;
                int n = col & 3;
                float bb = bias[col];
                f32x4 v = acc[mi][ni];
                #pragma unroll
                for (int r = 0; r < 4; r++) v[r] = (v[r] + bb) * gate[(rowBase + rowl0 + r)*4 + n];
                #pragma unroll
                for (int r = 0; r < 4; r++) v[r] += __shfl_xor(v[r], 1);
                #pragma unroll
                for (int r = 0; r < 4; r++) v[r] += __shfl_xor(v[r], 2);
                if ((lane & 3) == 0) {
                    int ul = ((w & 1) << 4) + ni*4 + (lm >> 2);
                    #pragma unroll
                    for (int r = 0; r < 4; r++)
                        sm.z[(rowl0 + r)*32 + ul] = v[r];
                }
            }
        }
        __syncthreads();
        float aw[9];
        #pragma unroll
        for (int i = 0; i < 9; i++) aw[i] = actw[i];
        int u0 = colBase >> 2;
        #pragma unroll
        for (int i = 0; i < TM/8; i++) {
            int idx = t + i*256;
            int row = idx >> 5, ul = idx & 31;
            int ug = u0 + ul;
            float zz = sm.z[idx];
            outH[(size_t)(rowBase + row)*outStride + ug] = __float2bfloat16(qact(zz, aw) * mask[ug]);
        }
    } else if (MODE == 5) {
        #pragma unroll
        for (int mi = 0; mi < MI; mi++) {
            int row0 = rowBase + qm + mi*16 + lq*4;
            #pragma unroll
            for (int ni = 0; ni < 4; ni++) {
                int col = colBase + qn + ni*16 + lm;
                if (col < 2048) {
                    float bb = bias[col];
                    #pragma unroll
                    for (int r = 0; r < 4; r++)
                        outH[(size_t)(row0 + r)*2048 + col] = __float2bfloat16(acc[mi][ni][r] + bb);
                } else if (col < 3072) {
                    int c = col - 2048;
                    float bb = bias2[c];
                    #pragma unroll
                    for (int r = 0; r < 4; r++)
                        outH2[(size_t)(row0 + r)*1024 + c] = __float2bfloat16(fast_tanh(acc[mi][ni][r] + bb));
                } else {
                    int c = col - 3072;
                    float bb = bias3[c];
                    #pragma unroll
                    for (int r = 0; r < 4; r++)
                        outF[(size_t)(row0 + r)*512 + c] = acc[mi][ni][r] + bb;
                }
            }
        }
    } else {  // MODE 3 (split-K partial, z in [0,4): partial 0 -> outF, z>0 -> outF2 + (z-1)*1M floats)
        float* of = bz ? (outF2 + (size_t)(bz - 1) * 1048576) : outF;
        #pragma unroll
        for (int mi = 0; mi < MI; mi++) {
            int row0 = rowBase + qm + mi*16 + lq*4;
            #pragma unroll
            for (int ni = 0; ni < 4; ni++) {
                int col = colBase + qn + ni*16 + lm;
                #pragma unroll
                for (int r = 0; r < 4; r++)
                    of[(size_t)(row0 + r)*outStride + col] = acc[mi][ni][r];
            }
        }
    }
}

template <int MODE, int TM>
__global__ __launch_bounds__(256, 2) void gemm_bt(
        const bf16* __restrict__ A, const bf16* __restrict__ Bt,
        int K, int lda, int ldb, int kOffset,
        const float* __restrict__ bias, const float* __restrict__ bias2,
        const float* __restrict__ bias3,
        float* __restrict__ outF, float* __restrict__ outF2,
        bf16* __restrict__ outH, bf16* __restrict__ outH2,
        const float* __restrict__ gate, const float* __restrict__ actw,
        const float* __restrict__ mask, int outStride) {
    __shared__ __align__(16) SMemT<TM> sm;
    gemm_core<MODE, TM>(blockIdx.x, blockIdx.y, blockIdx.z, sm,
                        A, Bt, K, lda, ldb, kOffset, bias, bias2, bias3,
                        outF, outF2, outH, outH2, gate, actw, mask, outStride);
}

// ---------------- G1 fused dispatch: capacity-matched interleave (round 19, kept) ----------------
__global__ __launch_bounds__(256, 2) void k_g1x(
        const bf16* __restrict__ xbf, const bf16* __restrict__ wT,
        const float* __restrict__ bias, bf16* __restrict__ hidden,
        const float* __restrict__ gate, const float* __restrict__ actw,
        const float* __restrict__ mask,
        const float* __restrict__ att_w, const float* __restrict__ write_w,
        const float* __restrict__ out_w, bf16* __restrict__ catT,
        const float* __restrict__ mem, bf16* __restrict__ memT) {
    __shared__ __align__(16) SMemT<128> sm;
    int bid = blockIdx.x, t = threadIdx.x;
    int gemmId = -1, trId;
    if (bid < 768) {
        int g = bid / 3, r = bid - g*3;
        if (r < 2) gemmId = g*2 + r;               // 0..511
        else       trId = g;                       // 0..255
    } else {
        trId = 256 + (bid - 768);                  // 256..2303
    }
    if (gemmId >= 0) {
        gemm_core<4, 128>(gemmId & 63, gemmId >> 6, 0, sm, xbf, wT, 1024, 1024, 1024, 0,
                          bias, nullptr, nullptr, nullptr, nullptr, hidden, nullptr,
                          gate, actw, mask, 2048);
    } else {
        int rel = trId;
        if (rel < 1024) {
            do_transpose(att_w, catT, 2048, 2048, rel & 31, rel >> 5, t, sm.tr);
        } else if (rel < 1536) {
            rel -= 1024;
            do_transpose(write_w, catT + 2048ull*2048, 2048, 1024, rel & 15, rel >> 4, t, sm.tr);
        } else if (rel < 1792) {
            rel -= 1536;
            do_transpose(out_w, catT + 3072ull*2048, 2048, 512, rel & 7, rel >> 3, t, sm.tr);
        } else {
            rel -= 1792;
            do_transpose(mem, memT, 2048, 1024, rel & 15, rel >> 4, t, sm.tr);
        }
    }
}

// ---------------- in-place row softmax over 2048 cols (bf16 buffer) ----------------
__global__ __launch_bounds__(256) void k_softmax(bf16* __restrict__ ratt) {
    int b = blockIdx.x, t = threadIdx.x, w = t >> 6, lane = t & 63;
    __shared__ float red[8];
    bf16* row = ratt + (size_t)b*2048;
    float v[8];
    float mx = -1e30f;
    #pragma unroll
    for (int j = 0; j < 8; j++) {
        v[j] = __bfloat162float(row[t + j*256]);
        mx = fmaxf(mx, v[j]);
    }
    #pragma unroll
    for (int off = 32; off; off >>= 1) mx = fmaxf(mx, __shfl_xor(mx, off));
    if (lane == 0) red[w] = mx;
    __syncthreads();
    mx = fmaxf(fmaxf(red[0], red[1]), fmaxf(red[2], red[3]));
    float s = 0.f;
    #pragma unroll
    for (int j = 0; j < 8; j++) { v[j] = __expf(v[j] - mx); s += v[j]; }
    #pragma unroll
    for (int off = 32; off; off >>= 1) s += __shfl_xor(s, off);
    if (lane == 0) red[4 + w] = s;
    __syncthreads();
    float inv = 1.f / (red[4] + red[5] + red[6] + red[7]);
    #pragma unroll
    for (int j = 0; j < 8; j++)
        row[t + j*256] = __float2bfloat16(v[j] * inv);
}

// ---------------- G5 fused dispatch: split-K read GEMM TM=128 (256 blocks = 1/CU) + colpart ----------------
// Round 20: TM=128 grid (8 n-tiles x 8 m-tiles x 4 z) = exactly 256 gemm blocks, 16 MFMA
// per barrier-pair (was 512 TM=64 blocks at 8 MFMA).
__global__ __launch_bounds__(256, 2) void k_g5x(
        const bf16* __restrict__ ratt, const bf16* __restrict__ memT,
        const bf16* __restrict__ cand,
        float* __restrict__ readv, float* __restrict__ readv2,
        float* __restrict__ part) {
    __shared__ __align__(16) SMemT<128> sm;
    int bid = blockIdx.x, t = threadIdx.x;
    if (bid < 256) {
        int bx = bid & 7, by = (bid >> 3) & 7, bz = bid >> 6;
        gemm_core<3, 128>(bx, by, bz, sm, ratt, memT, 512, 2048, 2048, 512,
                          nullptr, nullptr, nullptr, readv, readv2, nullptr, nullptr,
                          nullptr, nullptr, nullptr, 1024);
    } else {
        int rel = bid - 256;                       // 96 colpart blocks: 12 x 8
        int ct = rel % 12, rc = rel / 12;
        int col = ct*256 + t;
        const bf16* src; int stride, c;
        if (ct < 8) { src = ratt; stride = 2048; c = col; }
        else        { src = cand; stride = 1024; c = col - 2048; }
        float s = 0.f;
        int r0 = rc*128;
        for (int r2 = 0; r2 < 128; r2++)
            s += __bfloat162float(src[(size_t)(r0 + r2)*stride + c]);
        part[rc*3072 + col] = s;
    }
}

__global__ __launch_bounds__(256) void k_colfin(const float* __restrict__ part,
                                                const float* __restrict__ update_gate,
                                                float* __restrict__ u,
                                                float* __restrict__ cmean) {
    int col = blockIdx.x*256 + threadIdx.x;
    float s = 0.f;
    #pragma unroll
    for (int rc = 0; rc < 8; rc++) s += part[rc*3072 + col];
    s *= (1.f/1024.f);
    if (col < 2048) u[col] = s * update_gate[col];
    else            cmean[col - 2048] = s;
}

// ---------------- final fused dispatch: critic (512 blocks) + vectorized newmem (2048 blocks) ----------------
// critic: 2 rows/block, f32x4 weight loads (round-10 validated); sums 4 split-K read partials.
__global__ __launch_bounds__(256) void k_fin(
        const float* __restrict__ readv, const float* __restrict__ readv2,
        const float* __restrict__ preds, const bf16* __restrict__ hidden,
        const float* cw1, const float* cb1, const float* cw2, const float* cb2,
        const float* cw3, const float* cb3, const float* cw4, const float* cb4,
        const float* cw5, const float* cb5, const float* thr,
        float* __restrict__ out0,
        const float* __restrict__ mem, const float* __restrict__ u,
        const float* __restrict__ cmean, float* __restrict__ out1) {
    __shared__ __align__(16) float sx[2*1024];
    __shared__ __align__(16) float sp[2*512];
    __shared__ __align__(16) short sh[2*2048];
    __shared__ __align__(16) f32x4 part[2][32][8];
    __shared__ float feat[2][96];
    __shared__ float fused[2][64];
    __shared__ float gsh[2];
    int bid = blockIdx.x, t = threadIdx.x;
    if (bid >= 512) {
        // new_mem blend, f32x4-vectorized: idx over 2048x1024 f32 in groups of 4
        int idx = (bid - 512)*256 + t;             // f32x4 index, 524288 total
        int m = idx >> 8, d4 = idx & 255;
        float um = u[m];
        f32x4 m4 = ((const f32x4*)mem)[idx];
        f32x4 c4 = ((const f32x4*)cmean)[d4];
        f32x4 o;
        #pragma unroll
        for (int j = 0; j < 4; j++) o[j] = m4[j] * (1.f - um) + um * c4[j];
        ((f32x4*)out1)[idx] = o;
        return;
    }
    int b0 = bid * 2;
    int j4 = t & 7, kg = t >> 3;

    {
        const f32x4* r0 = (const f32x4*)(readv  + (size_t)b0*1024);
        const f32x4* r1 = (const f32x4*)(readv2 + (size_t)b0*1024);
        const f32x4* r2 = (const f32x4*)(readv2 + 1048576 + (size_t)b0*1024);
        const f32x4* r3 = (const f32x4*)(readv2 + 2097152 + (size_t)b0*1024);
        ((f32x4*)sx)[t]       = r0[t] + r1[t] + r2[t] + r3[t];
        ((f32x4*)sx)[t + 256] = r0[t + 256] + r1[t + 256] + r2[t + 256] + r3[t + 256];
    }
    ((f32x4*)sp)[t]       = ((const f32x4*)(preds + (size_t)b0*512))[t];
    ((s16x8*)sh)[t]       = ((const s16x8*)(hidden + (size_t)b0*2048))[t];
    ((s16x8*)sh)[t + 256] = ((const s16x8*)(hidden + (size_t)b0*2048))[t + 256];
    __syncthreads();

    {
        const f32x4* wv = (const f32x4*)cw1;
        f32x4 a0 = (f32x4){0,0,0,0}, a1 = (f32x4){0,0,0,0};
        int k0 = kg*32;
        #pragma unroll 4
        for (int k = k0; k < k0 + 32; k++) {
            f32x4 wq = wv[k*8 + j4];
            a0 += sx[k] * wq;
            a1 += sx[1024 + k] * wq;
        }
        part[0][kg][j4] = a0; part[1][kg][j4] = a1;
    }
    __syncthreads();
    if (t < 64) {
        int r = t >> 5, f = t & 31;
        float s = 0.f;
        #pragma unroll
        for (int i = 0; i < 32; i++) s += part[r][i][f >> 2][f & 3];
        feat[r][f] = fmaxf(s + cb1[f], 0.f);
    }
    __syncthreads();
    {
        const f32x4* wv = (const f32x4*)cw2;
        f32x4 a0 = (f32x4){0,0,0,0}, a1 = (f32x4){0,0,0,0};
        int k0 = kg*16;
        #pragma unroll 4
        for (int k = k0; k < k0 + 16; k++) {
            f32x4 wq = wv[k*8 + j4];
            a0 += sp[k] * wq;
            a1 += sp[512 + k] * wq;
        }
        part[0][kg][j4] = a0; part[1][kg][j4] = a1;
    }
    __syncthreads();
    if (t < 64) {
        int r = t >> 5, f = t & 31;
        float s = 0.f;
        #pragma unroll
        for (int i = 0; i < 32; i++) s += part[r][i][f >> 2][f & 3];
        feat[r][32 + f] = fmaxf(s + cb2[f], 0.f);
    }
    __syncthreads();
    {
        const f32x4* wv = (const f32x4*)cw3;
        f32x4 a0 = (f32x4){0,0,0,0}, a1 = (f32x4){0,0,0,0};
        int k0 = kg*64;
        #pragma unroll 4
        for (int k = k0; k < k0 + 64; k++) {
            f32x4 wq = wv[k*8 + j4];
            float h0 = __bfloat162float(*reinterpret_cast<const bf16*>(&sh[k]));
            float h1 = __bfloat162float(*reinterpret_cast<const bf16*>(&sh[2048 + k]));
            a0 += h0 * wq;
            a1 += h1 * wq;
        }
        part[0][kg][j4] = a0; part[1][kg][j4] = a1;
    }
    __syncthreads();
    if (t < 64) {
        int r = t >> 5, f = t & 31;
        float s = 0.f;
        #pragma unroll
        for (int i = 0; i < 32; i++) s += part[r][i][f >> 2][f & 3];
        feat[r][64 + f] = fmaxf(s + cb3[f], 0.f);
    }
    __syncthreads();
    if (t < 128) {
        int r = t >> 6, uu = t & 63;
        float s = 0.f;
        #pragma unroll 8
        for (int k = 0; k < 96; k++) s += feat[r][k] * cw4[k*64 + uu];
        fused[r][uu] = fmaxf(s + cb4[uu], 0.f);
    }
    __syncthreads();
    if (t < 128) {
        int r = t >> 6, lane = t & 63;
        float v = fused[r][lane] * cw5[lane*2];
        #pragma unroll
        for (int off = 32; off; off >>= 1) v += __shfl_xor(v, off);
        if (lane == 0)
            gsh[r] = 1.f / (1.f + __expf(-(v + cb5[0] - thr[0])));
    }
    __syncthreads();
    #pragma unroll
    for (int idx = t; idx < 1024; idx += 256) {
        int r = idx >> 9, o = idx & 511;
        out0[(size_t)(b0 + r)*512 + o] = sp[r*512 + o] * gsh[r];
    }
}

extern "C" void kernel_launch(void* const* d_in, const int* in_sizes, int n_in,
                              void* d_out, int out_size, void* d_ws, size_t ws_size,
                              hipStream_t stream) {
    const float* x        = (const float*)d_in[0];
    const float* w_       = (const float*)d_in[1];
    const float* b_bias   = (const float*)d_in[2];
    const float* gate_w   = (const float*)d_in[3];
    const float* gate_b   = (const float*)d_in[4];
    const float* act_w    = (const float*)d_in[5];
    const float* mask     = (const float*)d_in[6];
    const float* mem      = (const float*)d_in[7];
    const float* att_w    = (const float*)d_in[8];
    const float* att_b    = (const float*)d_in[9];
    const float* write_w  = (const float*)d_in[10];
    const float* write_b  = (const float*)d_in[11];
    const float* upd_gate = (const float*)d_in[12];
    const float* out_w    = (const float*)d_in[13];
    const float* out_b    = (const float*)d_in[14];
    const float* cw1 = (const float*)d_in[15]; const float* cb1 = (const float*)d_in[16];
    const float* cw2 = (const float*)d_in[17]; const float* cb2 = (const float*)d_in[18];
    const float* cw3 = (const float*)d_in[19]; const float* cb3 = (const float*)d_in[20];
    const float* cw4 = (const float*)d_in[21]; const float* cb4 = (const float*)d_in[22];
    const float* cw5 = (const float*)d_in[23]; const float* cb5 = (const float*)d_in[24];
    const float* thr = (const float*)d_in[25];

    char* ws = (char*)d_ws;
    float* gate   = (float*)(ws + GATE_OFF);
    float* actw   = (float*)(ws + ACTW_OFF);
    float* uvec   = (float*)(ws + U_OFF);
    float* cmean  = (float*)(ws + CMEAN_OFF);
    float* part   = (float*)(ws + PART_OFF);
    bf16*  hidden = (bf16*)(ws + HIDDEN_OFF);
    bf16*  ratt   = (bf16*)(ws + RATT_OFF);
    bf16*  cand   = (bf16*)(ws + CAND_OFF);
    float* preds  = (float*)(ws + PREDS_OFF);
    float* readv  = (float*)(ws + READ_OFF);
    float* readv2 = (float*)(ws + READ2_OFF);   // aliases wT head (dead after G1): 3 partials
    bf16*  xbf    = (bf16*)(ws + XBF_OFF);
    bf16*  wT     = (bf16*)(ws + WT_OFF);
    bf16*  catT   = (bf16*)(ws + CATT_OFF);
    bf16*  memT   = (bf16*)(ws + MEMT_OFF);

    float* out0 = (float*)d_out;            // (1024, 512)
    float* out1 = out0 + 1024*512;          // (2048, 1024)

    // prepass: cvt+gate fused + wT transpose — 3072 blocks
    k_prepass<<<3072, 256, 0, stream>>>(x, xbf, gate_w, gate_b, act_w, gate, actw, w_, wT);

    // G1 fused: hidden = qact((x@w + b)·gate)*mask  [M=1024,N=8192,K=1024, TM=128, 512 blocks]
    // + 2304 transpose blocks, capacity-matched interleave (first 768 = 2 gemm : 1 transpose)
    k_g1x<<<2816, 256, 0, stream>>>(xbf, wT, b_bias, hidden, gate, actw, mask,
                                    att_w, write_w, out_w, catT, mem, memT);

    // G234 fused: [att|write|out] heads  [M=1024, N=3584, K=2048] — TM=128, 224 blocks
    gemm_bt<5, 128><<<dim3(28, 8), 256, 0, stream>>>(hidden, catT, 2048, 2048, 2048, 0,
        att_b, write_b, out_b, preds, nullptr, ratt, cand, nullptr, nullptr, nullptr, 0);
    k_softmax<<<1024, 256, 0, stream>>>(ratt);
    // G5 fused: read = ratt @ mem split-K=4, TM=128 (256 blocks) + colpart (96 trailing)
    k_g5x<<<352, 256, 0, stream>>>(ratt, memT, cand, readv, readv2, part);

    k_colfin<<<12, 256, 0, stream>>>(part, upd_gate, uvec, cmean);
    // final: critic (512) + vectorized newmem (2048) in one dispatch
    k_fin<<<2560, 256, 0, stream>>>(readv, readv2, preds, hidden,
        cw1, cb1, cw2, cb2, cw3, cb3, cw4, cb4, cw5, cb5, thr, out0,
        mem, uvec, cmean, out1);
}